// Round 9
// baseline (582.990 us; speedup 1.0000x reference)
//
#include <hip/hip_runtime.h>

#define B_ 2
#define T_ 2048
#define D_ 2048
#define H_ 16
#define CONV_DIM_ 6144
#define NC_ 32   // chunks per sequence
#define CK_ 64   // chunk length

typedef __bf16 bf16;
typedef bf16 bf16x8 __attribute__((ext_vector_type(8)));
typedef bf16 bf16x4 __attribute__((ext_vector_type(4)));
typedef float floatx4 __attribute__((ext_vector_type(4)));

// async global->LDS 16B per lane: dest = wave-uniform base + lane*16
__device__ __forceinline__ void async_copy16(bf16* lds, const bf16* g) {
    auto* g1 = (const __attribute__((address_space(1))) unsigned int*)g;
    auto* l3 = (__attribute__((address_space(3))) unsigned int*)lds;
    __builtin_amdgcn_global_load_lds(g1, l3, 16, 0, 0);
}

// LDS-only barrier: __syncthreads() drains vmcnt(0) too, which kills in-flight
// register prefetch. Barriers in seq protect ONLY LDS data -> lgkmcnt(0) + raw
// s_barrier; global prefetch loads stay outstanding across it (compiler inserts
// vmcnt waits at the register use sites). sched_barrier pins ordering (rule #18).
__device__ __forceinline__ void lds_barrier() {
    asm volatile("s_waitcnt lgkmcnt(0)" ::: "memory");
    __builtin_amdgcn_sched_barrier(0);
    __builtin_amdgcn_s_barrier();
    __builtin_amdgcn_sched_barrier(0);
}

// ---------------- elementwise f32 -> bf16 ----------------
__global__ void cvt_bf16_kernel(const float* __restrict__ in, bf16* __restrict__ out, int n4) {
    int i = blockIdx.x * 256 + threadIdx.x;
    if (i < n4) {
        float4 v = ((const float4*)in)[i];
        bf16x4 o = { (bf16)v.x, (bf16)v.y, (bf16)v.z, (bf16)v.w };
        *(bf16x4*)(out + 4 * (size_t)i) = o;
    }
}

// ---------------- transpose f32 [R,Cn] -> bf16 [Cn,R] ----------------
__global__ void transpose_kernel(const float* __restrict__ in, bf16* __restrict__ out, int R, int Cn) {
    __shared__ float tile[32][33];
    const int c0 = blockIdx.x << 5, r0 = blockIdx.y << 5;
    const int tx = threadIdx.x & 31, ty = threadIdx.x >> 5;
#pragma unroll
    for (int i = 0; i < 4; ++i) {
        int r = ty + (i << 3);
        tile[r][tx] = in[(size_t)(r0 + r) * Cn + c0 + tx];
    }
    __syncthreads();
#pragma unroll
    for (int i = 0; i < 4; ++i) {
        int cc = ty + (i << 3);
        out[(size_t)(c0 + cc) * R + r0 + tx] = (bf16)tile[tx][cc];
    }
}

// ---------------- K transpose: kbuf [bh][t][128] -> kTb [bh][128][t] ----------------
__global__ void kt_transpose_kernel(const bf16* __restrict__ in, bf16* __restrict__ out) {
    __shared__ bf16 tile[32][34];
    const int bh = blockIdx.z;
    const int t0 = blockIdx.y << 5, d0 = blockIdx.x << 5;
    const int tx = threadIdx.x & 31, ty = threadIdx.x >> 5;  // 256 thr: ty 0..7
    const bf16* src = in + ((size_t)bh * T_ + t0) * 128 + d0;
#pragma unroll
    for (int i = 0; i < 4; ++i) {
        int r = ty + (i << 3);
        tile[r][tx] = src[(size_t)r * 128 + tx];
    }
    __syncthreads();
    bf16* dst = out + ((size_t)bh * 128 + d0) * T_ + t0;
#pragma unroll
    for (int i = 0; i < 4; ++i) {
        int rr = ty + (i << 3);
        dst[(size_t)rr * T_ + tx] = tile[tx][rr];
    }
}

// ---------------- Wb[2048,16],Wa[2048,16] -> Wba bf16 [32][2048] ----------------
__global__ void wba_cvt_kernel(const float* __restrict__ Wb, const float* __restrict__ Wa,
                               bf16* __restrict__ Wba) {
    int idx = blockIdx.x * 256 + threadIdx.x;  // 32768
    int d = idx >> 4, h = idx & 15;
    Wba[(size_t)h * 2048 + d]        = (bf16)Wb[idx];
    Wba[(size_t)(h + 16) * 2048 + d] = (bf16)Wa[idx];
}

// ---------------- bf16 MFMA GEMM: A[M,K] x Bt[N,K] -> C[M,N] ----------------
// 128x128 tile, 4 waves, BK=64, XOR-swizzled LDS, global_load_lds staging (m97).
template <typename OutT>
__global__ __launch_bounds__(256) void gemm_kernel(
    const bf16* __restrict__ A, const bf16* __restrict__ Bt, OutT* __restrict__ C,
    int M, int N, int K) {
    __shared__ bf16 As[128 * 64];
    __shared__ bf16 Bs[128 * 64];
    const int tid = threadIdx.x;
    const int m0 = blockIdx.y << 7;
    const int n0 = blockIdx.x << 7;
    const int wave = tid >> 6, lane = tid & 63;
    const int wm = (wave >> 1) << 6, wn = (wave & 1) << 6;
    const int lrow = lane & 15, quad = lane >> 4;
    const int rl = lane >> 3;
    const int c8s = (lane & 7) ^ (rl & 7);

    floatx4 acc[4][4];
#pragma unroll
    for (int mt = 0; mt < 4; ++mt)
#pragma unroll
        for (int nt = 0; nt < 4; ++nt)
            acc[mt][nt] = floatx4{0.f, 0.f, 0.f, 0.f};

    for (int k0 = 0; k0 < K; k0 += 64) {
        __syncthreads();
#pragma unroll
        for (int i = 0; i < 4; ++i) {
            const int slot = wave * 4 + i;           // 16 slots of 8 rows
            const int r = slot * 8 + rl;
            async_copy16(&As[slot * 512], A + (size_t)(m0 + r) * K + k0 + c8s * 8);
            async_copy16(&Bs[slot * 512], Bt + (size_t)(n0 + r) * K + k0 + c8s * 8);
        }
        __syncthreads();
#pragma unroll
        for (int kk = 0; kk < 64; kk += 32) {
            const int sw = (((kk >> 3) + quad) ^ (lrow & 7)) << 3;
            bf16x8 af[4], bfr[4];
#pragma unroll
            for (int mt = 0; mt < 4; ++mt) {
                af[mt]  = *(const bf16x8*)(&As[((wm + (mt << 4) + lrow) << 6) + sw]);
                bfr[mt] = *(const bf16x8*)(&Bs[((wn + (mt << 4) + lrow) << 6) + sw]);
            }
#pragma unroll
            for (int mt = 0; mt < 4; ++mt)
#pragma unroll
                for (int nt = 0; nt < 4; ++nt)
                    acc[mt][nt] = __builtin_amdgcn_mfma_f32_16x16x32_bf16(af[mt], bfr[nt], acc[mt][nt], 0, 0, 0);
        }
    }
#pragma unroll
    for (int mt = 0; mt < 4; ++mt)
#pragma unroll
        for (int nt = 0; nt < 4; ++nt) {
            const int col = n0 + wn + (nt << 4) + lrow;
            const int rowb = m0 + wm + (mt << 4) + (quad << 2);
#pragma unroll
            for (int i2 = 0; i2 < 4; ++i2)
                C[(size_t)(rowb + i2) * N + col] = (OutT)acc[mt][nt][i2];
        }
}

// ---------------- 256x256-tile bf16 GEMM, 8 waves, 8-phase counted-vmcnt pipeline ----------------
// Frozen at ~945 TF / 40% MfmaUtil (2 schedule rewrites no-delta -> stop rule).
__global__ __launch_bounds__(512, 2) void gemm256_kernel(
    const bf16* __restrict__ A, const bf16* __restrict__ Bt,
    bf16* __restrict__ C0, bf16* __restrict__ C1,
    int M, int Ncat, int K, int split, int ld0, int ld1) {
    __shared__ bf16 As[4][256 * 32];
    __shared__ bf16 Bs[4][256 * 32];
    const int tid = threadIdx.x;
    const int wave = tid >> 6, lane = tid & 63;
    const int quad = lane >> 4, lrow = lane & 15;
    const int wm = (wave >> 2) << 7;   // 0 / 128
    const int wn = (wave & 3) << 6;    // 0 / 64 / 128 / 192
    const int m0 = blockIdx.y << 8, n0 = blockIdx.x << 8;

    const bf16* gA[2];
    const bf16* gB[2];
#pragma unroll
    for (int i = 0; i < 2; ++i) {
        const int q = wave * 2 + i;
        const int u = (lane & 7) ^ (lane >> 3);          // pre-swizzle unit
        const int row = (q * 8 + (lane >> 3)) * 2 + (u >> 2);
        const int col = (u & 3) * 8;
        gA[i] = A  + (size_t)(m0 + row) * K + col;
        gB[i] = Bt + (size_t)(n0 + row) * K + col;
    }

    auto loff = [](int row, int qd) -> int {
        return ((row >> 1) << 6) + (((((row & 1) << 2) | qd) ^ ((row >> 1) & 7)) << 3);
    };

    floatx4 acc[8][4];
#pragma unroll
    for (int mt = 0; mt < 8; ++mt)
#pragma unroll
        for (int nt = 0; nt < 4; ++nt)
            acc[mt][nt] = floatx4{0.f, 0.f, 0.f, 0.f};

    const int KT = K >> 5;   // K=32 sub-tiles

#pragma unroll
    for (int t = 0; t < 3; ++t) {
        async_copy16(&As[t][(wave * 2 + 0) * 512], gA[0] + t * 32);
        async_copy16(&As[t][(wave * 2 + 1) * 512], gA[1] + t * 32);
        async_copy16(&Bs[t][(wave * 2 + 0) * 512], gB[0] + t * 32);
        async_copy16(&Bs[t][(wave * 2 + 1) * 512], gB[1] + t * 32);
    }
    asm volatile("s_waitcnt vmcnt(8)" ::: "memory");
    __builtin_amdgcn_s_barrier();

    for (int t = 0; t < KT; ++t) {
        const int b = t & 3;
        const bf16* as = &As[b][0];
        const bf16* bs = &Bs[b][0];
        // ---------------- phase A (mh = 0) ----------------
        bf16x8 bfr[4], af[4];
#pragma unroll
        for (int nt = 0; nt < 4; ++nt)
            bfr[nt] = *(const bf16x8*)(bs + loff(wn + nt * 16 + lrow, quad));
#pragma unroll
        for (int mt = 0; mt < 4; ++mt)
            af[mt] = *(const bf16x8*)(as + loff(wm + mt * 16 + lrow, quad));
        if (t + 2 < KT)       asm volatile("s_waitcnt vmcnt(4)" ::: "memory");
        else if (t + 2 == KT) asm volatile("s_waitcnt vmcnt(0)" ::: "memory");
        if (t + 3 < KT) {
            const int bn = (t + 3) & 3;
            async_copy16(&As[bn][(wave * 2 + 0) * 512], gA[0] + (t + 3) * 32);
            async_copy16(&As[bn][(wave * 2 + 1) * 512], gA[1] + (t + 3) * 32);
        }
        __builtin_amdgcn_s_barrier();
        asm volatile("s_waitcnt lgkmcnt(0)" ::: "memory");
        __builtin_amdgcn_sched_barrier(0);
        __builtin_amdgcn_s_setprio(1);
#pragma unroll
        for (int mt = 0; mt < 4; ++mt)
#pragma unroll
            for (int nt = 0; nt < 4; ++nt)
                acc[mt][nt] = __builtin_amdgcn_mfma_f32_16x16x32_bf16(
                    af[mt], bfr[nt], acc[mt][nt], 0, 0, 0);
        __builtin_amdgcn_s_setprio(0);
        __builtin_amdgcn_sched_barrier(0);
        __builtin_amdgcn_s_barrier();
        // ---------------- phase B (mh = 1) ----------------
#pragma unroll
        for (int mt = 0; mt < 4; ++mt)
            af[mt] = *(const bf16x8*)(as + loff(wm + 64 + mt * 16 + lrow, quad));
        if (t + 3 < KT) {
            const int bn = (t + 3) & 3;
            async_copy16(&Bs[bn][(wave * 2 + 0) * 512], gB[0] + (t + 3) * 32);
            async_copy16(&Bs[bn][(wave * 2 + 1) * 512], gB[1] + (t + 3) * 32);
        }
        __builtin_amdgcn_s_barrier();
        asm volatile("s_waitcnt lgkmcnt(0)" ::: "memory");
        __builtin_amdgcn_sched_barrier(0);
        __builtin_amdgcn_s_setprio(1);
#pragma unroll
        for (int mt = 0; mt < 4; ++mt)
#pragma unroll
            for (int nt = 0; nt < 4; ++nt)
                acc[4 + mt][nt] = __builtin_amdgcn_mfma_f32_16x16x32_bf16(
                    af[mt], bfr[nt], acc[4 + mt][nt], 0, 0, 0);
        __builtin_amdgcn_s_setprio(0);
        __builtin_amdgcn_sched_barrier(0);
        __builtin_amdgcn_s_barrier();
    }

    const bool second = (n0 >= split);
    bf16* Cp = second ? C1 : C0;
    const int ldc = second ? ld1 : ld0;
    const int nc0 = second ? n0 - split : n0;
#pragma unroll
    for (int mt = 0; mt < 8; ++mt)
#pragma unroll
        for (int nt = 0; nt < 4; ++nt) {
            const int col = nc0 + wn + nt * 16 + lrow;
            const int rowb = m0 + wm + mt * 16 + (quad << 2);
#pragma unroll
            for (int i2 = 0; i2 < 4; ++i2)
                Cp[(size_t)(rowb + i2) * ldc + col] = (bf16)acc[mt][nt][i2];
        }
}

// ---------------- depthwise causal conv (K=4) + silu + split + l2norm -> bf16 ----------------
__global__ __launch_bounds__(256) void conv_silu_kernel(
    const bf16* __restrict__ mixed, const float* __restrict__ cw,
    bf16* __restrict__ qb, bf16* __restrict__ kb, bf16* __restrict__ vb) {
    const int bt = blockIdx.y;
    const int t = bt & (T_ - 1);
    const int b = bt >> 11;
    const int c0 = blockIdx.x * 2048 + threadIdx.x * 8;
    const size_t base = (size_t)bt * CONV_DIM_ + c0;

    bf16x8 zz;
#pragma unroll
    for (int j = 0; j < 8; ++j) zz[j] = (bf16)0.f;
    const bf16x8 r3 = *(const bf16x8*)(mixed + base);
    const bf16x8 r2 = (t >= 1) ? *(const bf16x8*)(mixed + base - CONV_DIM_) : zz;
    const bf16x8 r1 = (t >= 2) ? *(const bf16x8*)(mixed + base - 2 * CONV_DIM_) : zz;
    const bf16x8 r0 = (t >= 3) ? *(const bf16x8*)(mixed + base - 3 * CONV_DIM_) : zz;

    const float4* cw4 = (const float4*)cw;
    float vals[8];
    float ss = 0.f;
#pragma unroll
    for (int j = 0; j < 8; ++j) {
        const float4 w = cw4[c0 + j];   // (w0,w1,w2,w3) for channel c0+j
        float acc = (float)r3[j] * w.w + (float)r2[j] * w.z +
                    (float)r1[j] * w.y + (float)r0[j] * w.x;
        const float sv = acc / (1.f + __expf(-acc));  // silu
        vals[j] = sv;
        ss += sv * sv;
    }

    if (c0 < 4096) {  // q or k: l2norm over the 128-channel head (16 lanes x 8)
#pragma unroll
        for (int o = 1; o < 16; o <<= 1) ss += __shfl_xor(ss, o);
        const float scale = rsqrtf(ss + 1e-6f);
        const bool isq = c0 < 2048;
        const float mul = isq ? scale * 0.08838834764831845f : scale;
        const int h = (c0 >> 7) & 15;
        const int d0 = c0 & 127;
        const size_t oidx = (((size_t)(b * H_ + h)) * T_ + t) * 128 + d0;
        bf16x8 o8;
#pragma unroll
        for (int j = 0; j < 8; ++j) o8[j] = (bf16)(vals[j] * mul);
        *(bf16x8*)((isq ? qb : kb) + oidx) = o8;
    } else {
        const int h = (c0 >> 7) & 15;
        const int d0 = c0 & 127;
        const size_t oidx = (((size_t)(b * H_ + h)) * T_ + t) * 128 + d0;
        bf16x8 o8;
#pragma unroll
        for (int j = 0; j < 8; ++j) o8[j] = (bf16)vals[j];
        *(bf16x8*)(vb + oidx) = o8;
    }
}

// ---------------- beta/g via skinny MFMA: [4096x2048] @ Wba^T[2048x32] ----------------
// 256 blocks x 1 wave x 16 rows (was 64 blocks = 1/4 of the CUs).
__global__ __launch_bounds__(64) void gbeta_mfma_kernel(
    const bf16* __restrict__ Xb, const bf16* __restrict__ Wba,
    const float* __restrict__ dtb, const float* __restrict__ Alog,
    float* __restrict__ gbuf, float* __restrict__ bbuf) {
    const int lane = threadIdx.x;
    const int ln = lane & 15, qd = lane >> 4;
    const int m0 = blockIdx.x * 16;
    floatx4 acc0 = {0.f, 0.f, 0.f, 0.f}, acc1 = {0.f, 0.f, 0.f, 0.f};
    const bf16* arow = Xb + (size_t)(m0 + ln) * 2048 + qd * 8;
    const bf16* b0 = Wba + (size_t)ln * 2048 + qd * 8;
    const bf16* b1 = Wba + (size_t)(16 + ln) * 2048 + qd * 8;
    for (int k = 0; k < 2048; k += 32) {
        bf16x8 af  = *(const bf16x8*)(arow + k);
        bf16x8 bf0 = *(const bf16x8*)(b0 + k);
        bf16x8 bf1 = *(const bf16x8*)(b1 + k);
        acc0 = __builtin_amdgcn_mfma_f32_16x16x32_bf16(af, bf0, acc0, 0, 0, 0);
        acc1 = __builtin_amdgcn_mfma_f32_16x16x32_bf16(af, bf1, acc1, 0, 0, 0);
    }
    const float dtbv = dtb[ln], al = __expf(Alog[ln]);
#pragma unroll
    for (int ii = 0; ii < 4; ++ii) {
        const int row = m0 + qd * 4 + ii;  // bt
        const int t = row & (T_ - 1), b = row >> 11;
        const size_t o = ((size_t)(b * H_ + ln)) * T_ + t;
        bbuf[o] = 1.f / (1.f + __expf(-acc0[ii]));
        const float xx = acc1[ii] + dtbv;
        const float sp = (xx > 15.f) ? xx : log1pf(__expf(xx));
        gbuf[o] = -al * sp;
    }
}

// ---------------- fused precompute: KK^T + QK^T (MFMA) -> decay/T/M, no global round-trip ----------------
__global__ __launch_bounds__(256) void qkkt_prep_kernel(
    const bf16* __restrict__ qb, const bf16* __restrict__ kb,
    const float* __restrict__ gbuf, const float* __restrict__ bbuf,
    float* __restrict__ lamg, float* __restrict__ ratiog,
    bf16* __restrict__ Tg, bf16* __restrict__ Mg) {
    const int u = blockIdx.x;
    const int bh = u >> 5, nc = u & 31;
    const int t0 = nc * CK_;
    const int tid = threadIdx.x, wave = tid >> 6, lane = tid & 63;
    const int qd = lane >> 4, ln = lane & 15;
    __shared__ bf16 Kc[64 * 136], Qc[64 * 136];
    __shared__ float Af[64 * 65], Mf[64 * 65];
    __shared__ float cv[64], bv[64];
    const size_t kbase = ((size_t)bh * T_ + t0) * 128;
#pragma unroll
    for (int it = 0; it < 4; ++it) {
        int idx = it * 256 + tid;
        int row = idx >> 4, c8 = idx & 15;
        *(uint4*)(&Kc[row * 136 + c8 * 8]) = *(const uint4*)(kb + kbase + row * 128 + c8 * 8);
        *(uint4*)(&Qc[row * 136 + c8 * 8]) = *(const uint4*)(qb + kbase + row * 128 + c8 * 8);
    }
    // wave 0: g/beta prefix scan (independent of Kc/Qc)
    if (wave == 0) {
        float g = gbuf[(size_t)bh * T_ + t0 + lane];
        float beta = bbuf[(size_t)bh * T_ + t0 + lane];
        float c = g;
#pragma unroll
        for (int off = 1; off < 64; off <<= 1) {
            float tval = __shfl_up(c, off);
            if (lane >= off) c += tval;
        }
        float c63 = __shfl(c, 63);
        lamg[(size_t)u * 64 + lane] = __expf(c);
        ratiog[(size_t)u * 64 + lane] = __expf(c63 - c);
        cv[lane] = c; bv[lane] = beta;
    }
    __syncthreads();
    // MFMA quadrants into registers, then LDS f32
    floatx4 rA[4], rM[4];
#pragma unroll
    for (int nt = 0; nt < 4; ++nt) {
        floatx4 accA = {0.f, 0.f, 0.f, 0.f}, accM = {0.f, 0.f, 0.f, 0.f};
#pragma unroll
        for (int kk = 0; kk < 4; ++kk) {
            bf16x8 bfr = *(const bf16x8*)(&Kc[(nt * 16 + ln) * 136 + kk * 32 + qd * 8]);
            bf16x8 afK = *(const bf16x8*)(&Kc[(wave * 16 + ln) * 136 + kk * 32 + qd * 8]);
            bf16x8 afQ = *(const bf16x8*)(&Qc[(wave * 16 + ln) * 136 + kk * 32 + qd * 8]);
            accA = __builtin_amdgcn_mfma_f32_16x16x32_bf16(afK, bfr, accA, 0, 0, 0);
            accM = __builtin_amdgcn_mfma_f32_16x16x32_bf16(afQ, bfr, accM, 0, 0, 0);
        }
        rA[nt] = accA; rM[nt] = accM;
    }
#pragma unroll
    for (int nt = 0; nt < 4; ++nt)
#pragma unroll
        for (int ii = 0; ii < 4; ++ii) {
            int i = wave * 16 + qd * 4 + ii, j = nt * 16 + ln;
            Af[i * 65 + j] = rA[nt][ii];
            Mf[i * 65 + j] = rM[nt][ii];
        }
    __syncthreads();
    // L-fill in place (256-wide)
#pragma unroll
    for (int r = 0; r < 16; ++r) {
        const int i = wave * 16 + r;
        float a = Af[i * 65 + lane];
        Af[i * 65 + lane] = (lane < i) ? bv[i] * __expf(cv[i] - cv[lane]) * a : 0.f;
    }
    __syncthreads();
    if (wave == 0) {
        // triangular solve: T = (I+L)^{-1}, lane = column
        float t[64];
#pragma unroll
        for (int i = 0; i < 64; ++i) t[i] = (i == lane) ? 1.f : 0.f;
#pragma unroll
        for (int j = 0; j < 63; ++j) {
#pragma unroll
            for (int i = j + 1; i < 64; ++i)
                t[i] -= Af[i * 65 + j] * t[j];
        }
#pragma unroll
        for (int i = 0; i < 64; ++i)
            Tg[(size_t)u * 4096 + i * 64 + lane] = (bf16)t[i];
    } else {
        // Mg mask+store: rows i = wave-1, wave-1+3, ...
        for (int i = wave - 1; i < 64; i += 3) {
            float m = Mf[i * 65 + lane];
            float mij = (lane <= i) ? __expf(cv[i] - cv[lane]) * m : 0.f;
            Mg[(size_t)u * 4096 + i * 64 + lane] = (bf16)mij;
        }
    }
}

// ---------------- sequential chunk loop ----------------
// 256 blocks = 8 v-splits (dv=16) x 32 bh. Raw lgkmcnt-only barriers keep the
// next-chunk register prefetch in flight across the chunk (no vmcnt(0) drain).
struct Pref {
    uint4 t2[2], m2[2];
    bf16x8 kf[4], qf[4];
    bf16x8 ktf[2][2];   // transposed K fragments for stage 5
    float rrv[4], vv[4], lam[4], bet[4], lamlast;
};

__device__ __forceinline__ void load_pref(
    Pref& p, int u, int t0, size_t kbase, int tid, int wave, int ln, int qd,
    int bh, int vbase,
    const bf16* __restrict__ qb, const bf16* __restrict__ kb, const bf16* __restrict__ vb,
    const bf16* __restrict__ kTb,
    const bf16* __restrict__ Tg, const bf16* __restrict__ Mg,
    const float* __restrict__ lamg, const float* __restrict__ ratiog,
    const float* __restrict__ bbuf) {
#pragma unroll
    for (int it = 0; it < 2; ++it) {
        int idx = it * 256 + tid;
        int row = idx >> 3, c8 = idx & 7;
        p.t2[it] = *(const uint4*)(Tg + (size_t)u * 4096 + row * 64 + c8 * 8);
        p.m2[it] = *(const uint4*)(Mg + (size_t)u * 4096 + row * 64 + c8 * 8);
    }
    const size_t rowoff = kbase + (size_t)(wave * 16 + ln) * 128;
#pragma unroll
    for (int kk = 0; kk < 4; ++kk) {
        p.kf[kk] = *(const bf16x8*)(kb + rowoff + kk * 32 + qd * 8);
        p.qf[kk] = *(const bf16x8*)(qb + rowoff + kk * 32 + qd * 8);
    }
    const int i0 = wave * 16 + qd * 4;
#pragma unroll
    for (int ii = 0; ii < 4; ++ii) {
        p.vv[ii]  = (float)vb[kbase + (size_t)(i0 + ii) * 128 + vbase + ln];
        p.lam[ii] = lamg[(size_t)u * 64 + i0 + ii];
        p.bet[ii] = bbuf[(size_t)bh * T_ + t0 + i0 + ii];
        p.rrv[ii] = ratiog[(size_t)u * 64 + i0 + ii];
    }
    p.lamlast = lamg[(size_t)u * 64 + 63];
    // transposed-K fragments: coalesced bf16x8 from kTb[bh][kd][t]
#pragma unroll
    for (int mt = 0; mt < 2; ++mt) {
        const int kd = (wave * 2 + mt) * 16 + ln;
        const bf16* kt_row = kTb + ((size_t)bh * 128 + kd) * T_ + t0;
#pragma unroll
        for (int kk2 = 0; kk2 < 2; ++kk2)
            p.ktf[mt][kk2] = *(const bf16x8*)(kt_row + kk2 * 32 + qd * 8);
    }
}

__global__ __launch_bounds__(256) void seq_kernel(
    const bf16* __restrict__ qb, const bf16* __restrict__ kb, const bf16* __restrict__ vb,
    const bf16* __restrict__ kTb,
    const bf16* __restrict__ Tg, const bf16* __restrict__ Mg,
    const float* __restrict__ lamg, const float* __restrict__ ratiog,
    const float* __restrict__ bbuf, float* __restrict__ ob) {
    const int bh = blockIdx.x & 31;
    const int vs = blockIdx.x >> 5;
    const int vbase = vs * 16;
    const int tid = threadIdx.x;
    const int wave = tid >> 6, lane = tid & 63;
    const int qd = lane >> 4, ln = lane & 15;

    __shared__ bf16 Tt[64 * 72], Mm[64 * 72];
    __shared__ bf16 bT[16 * 72], Dt[16 * 72], Dtr[16 * 72];
    __shared__ bf16 Sbf[2][16 * 136];   // ping-pong bf16 S (B-operand layout)

    for (int idx = tid; idx < 2 * 16 * 136; idx += 256)
        (&Sbf[0][0])[idx] = (bf16)0.f;

    // f32 master S in registers: lane (wave,ln,qd) owns S[k=(wave*2+mt)*16+qd*4+ii][v=ln]
    floatx4 Sreg[2] = { floatx4{0.f, 0.f, 0.f, 0.f}, floatx4{0.f, 0.f, 0.f, 0.f} };

    auto chunk_body = [&](Pref& cur, Pref& nxt, int nc, bf16* Srd, bf16* Swr) {
        const int t0 = nc * CK_;
        const size_t kbase = ((size_t)bh * T_ + t0) * 128;

        // stage LDS from cur regs (Tt/Mm only consumed after B1 -> no barrier here)
#pragma unroll
        for (int it = 0; it < 2; ++it) {
            int idx = it * 256 + tid;
            int row = idx >> 3, c8 = idx & 7;
            *(uint4*)(&Tt[row * 72 + c8 * 8]) = cur.t2[it];
            *(uint4*)(&Mm[row * 72 + c8 * 8]) = cur.m2[it];
        }

        // prefetch next chunk into regs (consumed one chunk later; loads stay
        // in flight across the lgkmcnt-only barriers below)
        {
            const int ncn = (nc + 1 < NC_) ? nc + 1 : nc;
            load_pref(nxt, bh * NC_ + ncn, ncn * CK_, ((size_t)bh * T_ + (size_t)ncn * CK_) * 128,
                      tid, wave, ln, qd, bh, vbase, qb, kb, vb, kTb, Tg, Mg, lamg, ratiog, bbuf);
        }

        // stage 1: KS = K @ S  and  QS = Q @ S (shared Srd reads; QS consumed in stage 4)
        floatx4 ks = {0.f, 0.f, 0.f, 0.f};
        floatx4 qs = {0.f, 0.f, 0.f, 0.f};
#pragma unroll
        for (int kk = 0; kk < 4; ++kk) {
            bf16x8 bf = *(const bf16x8*)(&Srd[ln * 136 + kk * 32 + qd * 8]);
            ks = __builtin_amdgcn_mfma_f32_16x16x32_bf16(cur.kf[kk], bf, ks, 0, 0, 0);
            qs = __builtin_amdgcn_mfma_f32_16x16x32_bf16(cur.qf[kk], bf, qs, 0, 0, 0);
        }
        // stage 2: b = beta*(V - lam*KS) -> bT[v][i]
        {
            const int i0 = wave * 16 + qd * 4;
            bf16x4 bw;
#pragma unroll
            for (int ii = 0; ii < 4; ++ii)
                bw[ii] = (bf16)(cur.bet[ii] * (cur.vv[ii] - cur.lam[ii] * ks[ii]));
            *(bf16x4*)(&bT[ln * 72 + i0]) = bw;
        }
        lds_barrier();  // B1

        // stage 3: D = T @ b -> Dt[v][i]; Dtr = D*rr
        {
            floatx4 acc = {0.f, 0.f, 0.f, 0.f};
#pragma unroll
            for (int kk = 0; kk < 2; ++kk) {
                bf16x8 af = *(const bf16x8*)(&Tt[(wave * 16 + ln) * 72 + kk * 32 + qd * 8]);
                bf16x8 bf = *(const bf16x8*)(&bT[ln * 72 + kk * 32 + qd * 8]);
                acc = __builtin_amdgcn_mfma_f32_16x16x32_bf16(af, bf, acc, 0, 0, 0);
            }
            const int i0 = wave * 16 + qd * 4;
            bf16x4 dw = { (bf16)acc[0], (bf16)acc[1], (bf16)acc[2], (bf16)acc[3] };
            *(bf16x4*)(&Dt[ln * 72 + i0]) = dw;
            bf16x4 dwr = { (bf16)(acc[0] * cur.rrv[0]), (bf16)(acc[1] * cur.rrv[1]),
                           (bf16)(acc[2] * cur.rrv[2]), (bf16)(acc[3] * cur.rrv[3]) };
            *(bf16x4*)(&Dtr[ln * 72 + i0]) = dwr;
        }
        lds_barrier();  // B2

        // stage 4: O = lam ⊙ QS + M@D -> global
        {
            floatx4 o;
#pragma unroll
            for (int ii = 0; ii < 4; ++ii) o[ii] = qs[ii] * cur.lam[ii];
#pragma unroll
            for (int kk = 0; kk < 2; ++kk) {
                bf16x8 af = *(const bf16x8*)(&Mm[(wave * 16 + ln) * 72 + kk * 32 + qd * 8]);
                bf16x8 bf = *(const bf16x8*)(&Dt[ln * 72 + kk * 32 + qd * 8]);
                o = __builtin_amdgcn_mfma_f32_16x16x32_bf16(af, bf, o, 0, 0, 0);
            }
            const int i0 = wave * 16 + qd * 4;
#pragma unroll
            for (int ii = 0; ii < 4; ++ii)
                ob[kbase + (size_t)(i0 + ii) * 128 + vbase + ln] = o[ii];
        }
        // stage 5: S = lamlast*S + K^T @ (rr⊙D); f32 in regs, bf16 -> Swr
#pragma unroll
        for (int mt = 0; mt < 2; ++mt) {
            const int kt = wave * 2 + mt;
            floatx4 acc = {0.f, 0.f, 0.f, 0.f};
#pragma unroll
            for (int kk = 0; kk < 2; ++kk) {
                bf16x8 bf = *(const bf16x8*)(&Dtr[ln * 72 + kk * 32 + qd * 8]);
                acc = __builtin_amdgcn_mfma_f32_16x16x32_bf16(cur.ktf[mt][kk], bf, acc, 0, 0, 0);
            }
            floatx4 sold = Sreg[mt];
#pragma unroll
            for (int ii = 0; ii < 4; ++ii) sold[ii] = sold[ii] * cur.lamlast + acc[ii];
            Sreg[mt] = sold;
            bf16x4 sb4 = { (bf16)sold[0], (bf16)sold[1], (bf16)sold[2], (bf16)sold[3] };
            *(bf16x4*)(&Swr[ln * 136 + kt * 16 + qd * 4]) = sb4;
        }
        lds_barrier();  // B3
    };

    Pref pA, pB;
    load_pref(pA, bh * NC_, 0, (size_t)bh * T_ * 128, tid, wave, ln, qd, bh, vbase,
              qb, kb, vb, kTb, Tg, Mg, lamg, ratiog, bbuf);
    __syncthreads();

#pragma unroll 1
    for (int nc2 = 0; nc2 < NC_; nc2 += 2) {
        chunk_body(pA, pB, nc2,     &Sbf[0][0], &Sbf[1][0]);
        chunk_body(pB, pA, nc2 + 1, &Sbf[1][0], &Sbf[0][0]);
    }
}

// ---------------- o = o*silu(z); RMSNorm over DV; -> bf16 ----------------
// 4 heads per 256-thread block (head = one 64-lane wave).
__global__ __launch_bounds__(256) void gated_norm_kernel(
    const float* __restrict__ ob, const bf16* __restrict__ z,
    const float* __restrict__ nw, bf16* __restrict__ onorm) {
    const int idx = blockIdx.x * 4 + (threadIdx.x >> 6);  // B*T*H
    const int h = idx & (H_ - 1);
    const int bt = idx >> 4;
    const int t = bt & (T_ - 1);
    const int b = bt >> 11;
    const int tid = threadIdx.x & 63;
    const size_t obase = (((size_t)(b * H_ + h)) * T_ + t) * 128;
    const size_t zbase = (size_t)bt * 2048 + (h << 7);
    float o1 = ob[obase + tid], o2 = ob[obase + tid + 64];
    const float z1 = (float)z[zbase + tid], z2 = (float)z[zbase + tid + 64];
    o1 *= z1 / (1.f + __expf(-z1));
    o2 *= z2 / (1.f + __expf(-z2));
    float ss = o1 * o1 + o2 * o2;
#pragma unroll
    for (int o = 1; o < 64; o <<= 1) ss += __shfl_xor(ss, o);
    const float scale = rsqrtf(ss * (1.f / 128.f) + 1e-6f);
    onorm[zbase + tid]      = (bf16)(o1 * scale * nw[tid]);
    onorm[zbase + tid + 64] = (bf16)(o2 * scale * nw[tid + 64]);
}

extern "C" void kernel_launch(void* const* d_in, const int* in_sizes, int n_in,
                              void* d_out, int out_size, void* d_ws, size_t ws_size,
                              hipStream_t stream) {
    const float* X    = (const float*)d_in[0];
    const float* Wqkv = (const float*)d_in[1];
    const float* cw   = (const float*)d_in[2];
    const float* Wz   = (const float*)d_in[3];
    const float* Wb   = (const float*)d_in[4];
    const float* Wa   = (const float*)d_in[5];
    const float* dtb  = (const float*)d_in[6];
    const float* Alog = (const float*)d_in[7];
    const float* nw   = (const float*)d_in[8];
    const float* Wout = (const float*)d_in[9];
    float* out = (float*)d_out;

    char* ws = (char*)d_ws;
    size_t off = 0;
    auto alloc = [&](size_t bytes) -> char* {
        char* p = ws + off;
        off += (bytes + 255) & ~(size_t)255;
        return p;
    };
    bf16*  Xb      = (bf16*)alloc((size_t)B_ * T_ * D_ * 2);
    // Wcat = [Wqkv^T (6144 rows) ; Wz^T (2048 rows)] -> 8192 x 2048 bf16
    char*  wcat_p  = alloc((size_t)8192 * 2048 * 2);
    bf16*  Wcat    = (bf16*)wcat_p;
    bf16*  Woutt   = (bf16*)alloc((size_t)D_ * D_ * 2);
    bf16*  Wba     = (bf16*)alloc((size_t)32 * 2048 * 2);
    char*  mixed_p = alloc((size_t)B_ * T_ * CONV_DIM_ * 2);
    bf16*  mixedb  = (bf16*)mixed_p;
    bf16*  zb      = (bf16*)alloc((size_t)B_ * T_ * D_ * 2);
    bf16*  kbuf    = (bf16*)alloc((size_t)B_ * T_ * D_ * 2);
    bf16*  vbuf    = (bf16*)alloc((size_t)B_ * T_ * D_ * 2);
    bf16*  kTb     = (bf16*)alloc((size_t)B_ * H_ * 128 * T_ * 2);
    float* gbuf    = (float*)alloc((size_t)B_ * T_ * H_ * 4);
    float* bbuf    = (float*)alloc((size_t)B_ * T_ * H_ * 4);
    bf16*  Tg      = (bf16*)alloc((size_t)1024 * 4096 * 2);
    bf16*  Mg      = (bf16*)alloc((size_t)1024 * 4096 * 2);
    float* lamg    = (float*)alloc((size_t)1024 * 64 * 4);
    float* ratiog  = (float*)alloc((size_t)1024 * 64 * 4);
    // aliases (stream-order safe):
    bf16*  qbuf    = (bf16*)wcat_p;
    float* obuf    = (float*)mixed_p;
    bf16*  onorm   = (bf16*)Xb;

    cvt_bf16_kernel<<<dim3((B_ * T_ * D_ / 4 + 255) / 256), dim3(256), 0, stream>>>(X, Xb, B_ * T_ * D_ / 4);
    transpose_kernel<<<dim3(CONV_DIM_ / 32, D_ / 32), dim3(256), 0, stream>>>(Wqkv, Wcat, D_, CONV_DIM_);
    transpose_kernel<<<dim3(D_ / 32, D_ / 32), dim3(256), 0, stream>>>(Wz, Wcat + (size_t)CONV_DIM_ * D_, D_, D_);
    transpose_kernel<<<dim3(D_ / 32, D_ / 32), dim3(256), 0, stream>>>(Wout, Woutt, D_, D_);
    wba_cvt_kernel<<<dim3(128), dim3(256), 0, stream>>>(Wb, Wa, Wba);

    // fused QKV+Z projection: [4096 x 2048] @ [2048 x 8192]; cols<6144 -> mixed, else -> z
    gemm256_kernel<<<dim3(8192 / 256, B_ * T_ / 256), dim3(512), 0, stream>>>(
        Xb, Wcat, mixedb, zb, B_ * T_, 8192, D_, CONV_DIM_, CONV_DIM_, D_);

    gbeta_mfma_kernel<<<dim3(256), dim3(64), 0, stream>>>(Xb, Wba, dtb, Alog, gbuf, bbuf);
    conv_silu_kernel<<<dim3(CONV_DIM_ / 2048, B_ * T_), dim3(256), 0, stream>>>(mixedb, cw, qbuf, kbuf, vbuf);

    kt_transpose_kernel<<<dim3(128 / 32, T_ / 32, B_ * H_), dim3(256), 0, stream>>>(kbuf, kTb);
    qkkt_prep_kernel<<<dim3(1024), dim3(256), 0, stream>>>(qbuf, kbuf, gbuf, bbuf, lamg, ratiog, Tg, Mg);
    seq_kernel<<<dim3(256), dim3(256), 0, stream>>>(qbuf, kbuf, vbuf, kTb, Tg, Mg, lamg, ratiog, bbuf, obuf);

    gated_norm_kernel<<<dim3(B_ * T_ * H_ / 4), dim3(256), 0, stream>>>(obuf, zb, nw, onorm);

    gemm_kernel<float><<<dim3(D_ / 128, B_ * T_ / 128), dim3(256), 0, stream>>>(
        onorm, Woutt, out, B_ * T_, D_, D_);
}

// Round 10
// 563.428 us; speedup vs baseline: 1.0347x; 1.0347x over previous
//
#include <hip/hip_runtime.h>

#define B_ 2
#define T_ 2048
#define D_ 2048
#define H_ 16
#define CONV_DIM_ 6144
#define NC_ 32   // chunks per sequence
#define CK_ 64   // chunk length

typedef __bf16 bf16;
typedef bf16 bf16x8 __attribute__((ext_vector_type(8)));
typedef bf16 bf16x4 __attribute__((ext_vector_type(4)));
typedef float floatx4 __attribute__((ext_vector_type(4)));

// async global->LDS 16B per lane: dest = wave-uniform base + lane*16
__device__ __forceinline__ void async_copy16(bf16* lds, const bf16* g) {
    auto* g1 = (const __attribute__((address_space(1))) unsigned int*)g;
    auto* l3 = (__attribute__((address_space(3))) unsigned int*)lds;
    __builtin_amdgcn_global_load_lds(g1, l3, 16, 0, 0);
}

// ---------------- elementwise f32 -> bf16 ----------------
__global__ void cvt_bf16_kernel(const float* __restrict__ in, bf16* __restrict__ out, int n4) {
    int i = blockIdx.x * 256 + threadIdx.x;
    if (i < n4) {
        float4 v = ((const float4*)in)[i];
        bf16x4 o = { (bf16)v.x, (bf16)v.y, (bf16)v.z, (bf16)v.w };
        *(bf16x4*)(out + 4 * (size_t)i) = o;
    }
}

// ---------------- transpose f32 [R,Cn] -> bf16 [Cn,R] ----------------
__global__ void transpose_kernel(const float* __restrict__ in, bf16* __restrict__ out, int R, int Cn) {
    __shared__ float tile[32][33];
    const int c0 = blockIdx.x << 5, r0 = blockIdx.y << 5;
    const int tx = threadIdx.x & 31, ty = threadIdx.x >> 5;
#pragma unroll
    for (int i = 0; i < 4; ++i) {
        int r = ty + (i << 3);
        tile[r][tx] = in[(size_t)(r0 + r) * Cn + c0 + tx];
    }
    __syncthreads();
#pragma unroll
    for (int i = 0; i < 4; ++i) {
        int cc = ty + (i << 3);
        out[(size_t)(c0 + cc) * R + r0 + tx] = (bf16)tile[tx][cc];
    }
}

// ---------------- K transpose: kbuf [bh][t][128] -> kTb [bh][128][t] ----------------
__global__ void kt_transpose_kernel(const bf16* __restrict__ in, bf16* __restrict__ out) {
    __shared__ bf16 tile[32][34];
    const int bh = blockIdx.z;
    const int t0 = blockIdx.y << 5, d0 = blockIdx.x << 5;
    const int tx = threadIdx.x & 31, ty = threadIdx.x >> 5;  // 256 thr: ty 0..7
    const bf16* src = in + ((size_t)bh * T_ + t0) * 128 + d0;
#pragma unroll
    for (int i = 0; i < 4; ++i) {
        int r = ty + (i << 3);
        tile[r][tx] = src[(size_t)r * 128 + tx];
    }
    __syncthreads();
    bf16* dst = out + ((size_t)bh * 128 + d0) * T_ + t0;
#pragma unroll
    for (int i = 0; i < 4; ++i) {
        int rr = ty + (i << 3);
        dst[(size_t)rr * T_ + tx] = tile[tx][rr];
    }
}

// ---------------- Wb[2048,16],Wa[2048,16] -> Wba bf16 [32][2048] ----------------
__global__ void wba_cvt_kernel(const float* __restrict__ Wb, const float* __restrict__ Wa,
                               bf16* __restrict__ Wba) {
    int idx = blockIdx.x * 256 + threadIdx.x;  // 32768
    int d = idx >> 4, h = idx & 15;
    Wba[(size_t)h * 2048 + d]        = (bf16)Wb[idx];
    Wba[(size_t)(h + 16) * 2048 + d] = (bf16)Wa[idx];
}

// ---------------- bf16 MFMA GEMM: A[M,K] x Bt[N,K] -> C[M,N] ----------------
// 128x128 tile, 4 waves, BK=64, XOR-swizzled LDS, global_load_lds staging (m97).
template <typename OutT>
__global__ __launch_bounds__(256) void gemm_kernel(
    const bf16* __restrict__ A, const bf16* __restrict__ Bt, OutT* __restrict__ C,
    int M, int N, int K) {
    __shared__ bf16 As[128 * 64];
    __shared__ bf16 Bs[128 * 64];
    const int tid = threadIdx.x;
    const int m0 = blockIdx.y << 7;
    const int n0 = blockIdx.x << 7;
    const int wave = tid >> 6, lane = tid & 63;
    const int wm = (wave >> 1) << 6, wn = (wave & 1) << 6;
    const int lrow = lane & 15, quad = lane >> 4;
    const int rl = lane >> 3;
    const int c8s = (lane & 7) ^ (rl & 7);

    floatx4 acc[4][4];
#pragma unroll
    for (int mt = 0; mt < 4; ++mt)
#pragma unroll
        for (int nt = 0; nt < 4; ++nt)
            acc[mt][nt] = floatx4{0.f, 0.f, 0.f, 0.f};

    for (int k0 = 0; k0 < K; k0 += 64) {
        __syncthreads();
#pragma unroll
        for (int i = 0; i < 4; ++i) {
            const int slot = wave * 4 + i;           // 16 slots of 8 rows
            const int r = slot * 8 + rl;
            async_copy16(&As[slot * 512], A + (size_t)(m0 + r) * K + k0 + c8s * 8);
            async_copy16(&Bs[slot * 512], Bt + (size_t)(n0 + r) * K + k0 + c8s * 8);
        }
        __syncthreads();
#pragma unroll
        for (int kk = 0; kk < 64; kk += 32) {
            const int sw = (((kk >> 3) + quad) ^ (lrow & 7)) << 3;
            bf16x8 af[4], bfr[4];
#pragma unroll
            for (int mt = 0; mt < 4; ++mt) {
                af[mt]  = *(const bf16x8*)(&As[((wm + (mt << 4) + lrow) << 6) + sw]);
                bfr[mt] = *(const bf16x8*)(&Bs[((wn + (mt << 4) + lrow) << 6) + sw]);
            }
#pragma unroll
            for (int mt = 0; mt < 4; ++mt)
#pragma unroll
                for (int nt = 0; nt < 4; ++nt)
                    acc[mt][nt] = __builtin_amdgcn_mfma_f32_16x16x32_bf16(af[mt], bfr[nt], acc[mt][nt], 0, 0, 0);
        }
    }
#pragma unroll
    for (int mt = 0; mt < 4; ++mt)
#pragma unroll
        for (int nt = 0; nt < 4; ++nt) {
            const int col = n0 + wn + (nt << 4) + lrow;
            const int rowb = m0 + wm + (mt << 4) + (quad << 2);
#pragma unroll
            for (int i2 = 0; i2 < 4; ++i2)
                C[(size_t)(rowb + i2) * N + col] = (OutT)acc[mt][nt][i2];
        }
}

// ---------------- 256x256-tile bf16 GEMM, 8 waves, 8-phase counted-vmcnt pipeline ----------------
// Frozen at ~945 TF / 40% MfmaUtil (2 schedule rewrites no-delta -> stop rule).
__global__ __launch_bounds__(512, 2) void gemm256_kernel(
    const bf16* __restrict__ A, const bf16* __restrict__ Bt,
    bf16* __restrict__ C0, bf16* __restrict__ C1,
    int M, int Ncat, int K, int split, int ld0, int ld1) {
    __shared__ bf16 As[4][256 * 32];
    __shared__ bf16 Bs[4][256 * 32];
    const int tid = threadIdx.x;
    const int wave = tid >> 6, lane = tid & 63;
    const int quad = lane >> 4, lrow = lane & 15;
    const int wm = (wave >> 2) << 7;   // 0 / 128
    const int wn = (wave & 3) << 6;    // 0 / 64 / 128 / 192
    const int m0 = blockIdx.y << 8, n0 = blockIdx.x << 8;

    const bf16* gA[2];
    const bf16* gB[2];
#pragma unroll
    for (int i = 0; i < 2; ++i) {
        const int q = wave * 2 + i;
        const int u = (lane & 7) ^ (lane >> 3);          // pre-swizzle unit
        const int row = (q * 8 + (lane >> 3)) * 2 + (u >> 2);
        const int col = (u & 3) * 8;
        gA[i] = A  + (size_t)(m0 + row) * K + col;
        gB[i] = Bt + (size_t)(n0 + row) * K + col;
    }

    auto loff = [](int row, int qd) -> int {
        return ((row >> 1) << 6) + (((((row & 1) << 2) | qd) ^ ((row >> 1) & 7)) << 3);
    };

    floatx4 acc[8][4];
#pragma unroll
    for (int mt = 0; mt < 8; ++mt)
#pragma unroll
        for (int nt = 0; nt < 4; ++nt)
            acc[mt][nt] = floatx4{0.f, 0.f, 0.f, 0.f};

    const int KT = K >> 5;   // K=32 sub-tiles

#pragma unroll
    for (int t = 0; t < 3; ++t) {
        async_copy16(&As[t][(wave * 2 + 0) * 512], gA[0] + t * 32);
        async_copy16(&As[t][(wave * 2 + 1) * 512], gA[1] + t * 32);
        async_copy16(&Bs[t][(wave * 2 + 0) * 512], gB[0] + t * 32);
        async_copy16(&Bs[t][(wave * 2 + 1) * 512], gB[1] + t * 32);
    }
    asm volatile("s_waitcnt vmcnt(8)" ::: "memory");
    __builtin_amdgcn_s_barrier();

    for (int t = 0; t < KT; ++t) {
        const int b = t & 3;
        const bf16* as = &As[b][0];
        const bf16* bs = &Bs[b][0];
        // ---------------- phase A (mh = 0) ----------------
        bf16x8 bfr[4], af[4];
#pragma unroll
        for (int nt = 0; nt < 4; ++nt)
            bfr[nt] = *(const bf16x8*)(bs + loff(wn + nt * 16 + lrow, quad));
#pragma unroll
        for (int mt = 0; mt < 4; ++mt)
            af[mt] = *(const bf16x8*)(as + loff(wm + mt * 16 + lrow, quad));
        if (t + 2 < KT)       asm volatile("s_waitcnt vmcnt(4)" ::: "memory");
        else if (t + 2 == KT) asm volatile("s_waitcnt vmcnt(0)" ::: "memory");
        if (t + 3 < KT) {
            const int bn = (t + 3) & 3;
            async_copy16(&As[bn][(wave * 2 + 0) * 512], gA[0] + (t + 3) * 32);
            async_copy16(&As[bn][(wave * 2 + 1) * 512], gA[1] + (t + 3) * 32);
        }
        __builtin_amdgcn_s_barrier();
        asm volatile("s_waitcnt lgkmcnt(0)" ::: "memory");
        __builtin_amdgcn_sched_barrier(0);
        __builtin_amdgcn_s_setprio(1);
#pragma unroll
        for (int mt = 0; mt < 4; ++mt)
#pragma unroll
            for (int nt = 0; nt < 4; ++nt)
                acc[mt][nt] = __builtin_amdgcn_mfma_f32_16x16x32_bf16(
                    af[mt], bfr[nt], acc[mt][nt], 0, 0, 0);
        __builtin_amdgcn_s_setprio(0);
        __builtin_amdgcn_sched_barrier(0);
        __builtin_amdgcn_s_barrier();
        // ---------------- phase B (mh = 1) ----------------
#pragma unroll
        for (int mt = 0; mt < 4; ++mt)
            af[mt] = *(const bf16x8*)(as + loff(wm + 64 + mt * 16 + lrow, quad));
        if (t + 3 < KT) {
            const int bn = (t + 3) & 3;
            async_copy16(&Bs[bn][(wave * 2 + 0) * 512], gB[0] + (t + 3) * 32);
            async_copy16(&Bs[bn][(wave * 2 + 1) * 512], gB[1] + (t + 3) * 32);
        }
        __builtin_amdgcn_s_barrier();
        asm volatile("s_waitcnt lgkmcnt(0)" ::: "memory");
        __builtin_amdgcn_sched_barrier(0);
        __builtin_amdgcn_s_setprio(1);
#pragma unroll
        for (int mt = 0; mt < 4; ++mt)
#pragma unroll
            for (int nt = 0; nt < 4; ++nt)
                acc[4 + mt][nt] = __builtin_amdgcn_mfma_f32_16x16x32_bf16(
                    af[mt], bfr[nt], acc[4 + mt][nt], 0, 0, 0);
        __builtin_amdgcn_s_setprio(0);
        __builtin_amdgcn_sched_barrier(0);
        __builtin_amdgcn_s_barrier();
    }

    const bool second = (n0 >= split);
    bf16* Cp = second ? C1 : C0;
    const int ldc = second ? ld1 : ld0;
    const int nc0 = second ? n0 - split : n0;
#pragma unroll
    for (int mt = 0; mt < 8; ++mt)
#pragma unroll
        for (int nt = 0; nt < 4; ++nt) {
            const int col = nc0 + wn + nt * 16 + lrow;
            const int rowb = m0 + wm + mt * 16 + (quad << 2);
#pragma unroll
            for (int i2 = 0; i2 < 4; ++i2)
                Cp[(size_t)(rowb + i2) * ldc + col] = (bf16)acc[mt][nt][i2];
        }
}

// ---------------- depthwise causal conv (K=4) + silu + split + l2norm -> bf16 ----------------
__global__ __launch_bounds__(256) void conv_silu_kernel(
    const bf16* __restrict__ mixed, const float* __restrict__ cw,
    bf16* __restrict__ qb, bf16* __restrict__ kb, bf16* __restrict__ vb) {
    const int bt = blockIdx.y;
    const int t = bt & (T_ - 1);
    const int b = bt >> 11;
    const int c0 = blockIdx.x * 2048 + threadIdx.x * 8;
    const size_t base = (size_t)bt * CONV_DIM_ + c0;

    bf16x8 zz;
#pragma unroll
    for (int j = 0; j < 8; ++j) zz[j] = (bf16)0.f;
    const bf16x8 r3 = *(const bf16x8*)(mixed + base);
    const bf16x8 r2 = (t >= 1) ? *(const bf16x8*)(mixed + base - CONV_DIM_) : zz;
    const bf16x8 r1 = (t >= 2) ? *(const bf16x8*)(mixed + base - 2 * CONV_DIM_) : zz;
    const bf16x8 r0 = (t >= 3) ? *(const bf16x8*)(mixed + base - 3 * CONV_DIM_) : zz;

    const float4* cw4 = (const float4*)cw;
    float vals[8];
    float ss = 0.f;
#pragma unroll
    for (int j = 0; j < 8; ++j) {
        const float4 w = cw4[c0 + j];   // (w0,w1,w2,w3) for channel c0+j
        float acc = (float)r3[j] * w.w + (float)r2[j] * w.z +
                    (float)r1[j] * w.y + (float)r0[j] * w.x;
        const float sv = acc / (1.f + __expf(-acc));  // silu
        vals[j] = sv;
        ss += sv * sv;
    }

    if (c0 < 4096) {  // q or k: l2norm over the 128-channel head (16 lanes x 8)
#pragma unroll
        for (int o = 1; o < 16; o <<= 1) ss += __shfl_xor(ss, o);
        const float scale = rsqrtf(ss + 1e-6f);
        const bool isq = c0 < 2048;
        const float mul = isq ? scale * 0.08838834764831845f : scale;
        const int h = (c0 >> 7) & 15;
        const int d0 = c0 & 127;
        const size_t oidx = (((size_t)(b * H_ + h)) * T_ + t) * 128 + d0;
        bf16x8 o8;
#pragma unroll
        for (int j = 0; j < 8; ++j) o8[j] = (bf16)(vals[j] * mul);
        *(bf16x8*)((isq ? qb : kb) + oidx) = o8;
    } else {
        const int h = (c0 >> 7) & 15;
        const int d0 = c0 & 127;
        const size_t oidx = (((size_t)(b * H_ + h)) * T_ + t) * 128 + d0;
        bf16x8 o8;
#pragma unroll
        for (int j = 0; j < 8; ++j) o8[j] = (bf16)vals[j];
        *(bf16x8*)(vb + oidx) = o8;
    }
}

// ---------------- beta/g via skinny MFMA: [4096x2048] @ Wba^T[2048x32] ----------------
// 256 blocks x 1 wave x 16 rows (was 64 blocks = 1/4 of the CUs).
__global__ __launch_bounds__(64) void gbeta_mfma_kernel(
    const bf16* __restrict__ Xb, const bf16* __restrict__ Wba,
    const float* __restrict__ dtb, const float* __restrict__ Alog,
    float* __restrict__ gbuf, float* __restrict__ bbuf) {
    const int lane = threadIdx.x;
    const int ln = lane & 15, qd = lane >> 4;
    const int m0 = blockIdx.x * 16;
    floatx4 acc0 = {0.f, 0.f, 0.f, 0.f}, acc1 = {0.f, 0.f, 0.f, 0.f};
    const bf16* arow = Xb + (size_t)(m0 + ln) * 2048 + qd * 8;
    const bf16* b0 = Wba + (size_t)ln * 2048 + qd * 8;
    const bf16* b1 = Wba + (size_t)(16 + ln) * 2048 + qd * 8;
    for (int k = 0; k < 2048; k += 32) {
        bf16x8 af  = *(const bf16x8*)(arow + k);
        bf16x8 bf0 = *(const bf16x8*)(b0 + k);
        bf16x8 bf1 = *(const bf16x8*)(b1 + k);
        acc0 = __builtin_amdgcn_mfma_f32_16x16x32_bf16(af, bf0, acc0, 0, 0, 0);
        acc1 = __builtin_amdgcn_mfma_f32_16x16x32_bf16(af, bf1, acc1, 0, 0, 0);
    }
    const float dtbv = dtb[ln], al = __expf(Alog[ln]);
#pragma unroll
    for (int ii = 0; ii < 4; ++ii) {
        const int row = m0 + qd * 4 + ii;  // bt
        const int t = row & (T_ - 1), b = row >> 11;
        const size_t o = ((size_t)(b * H_ + ln)) * T_ + t;
        bbuf[o] = 1.f / (1.f + __expf(-acc0[ii]));
        const float xx = acc1[ii] + dtbv;
        const float sp = (xx > 15.f) ? xx : log1pf(__expf(xx));
        gbuf[o] = -al * sp;
    }
}

// ---------------- fused precompute: KK^T + QK^T (MFMA) -> decay/T/M, no global round-trip ----------------
__global__ __launch_bounds__(256) void qkkt_prep_kernel(
    const bf16* __restrict__ qb, const bf16* __restrict__ kb,
    const float* __restrict__ gbuf, const float* __restrict__ bbuf,
    float* __restrict__ lamg, float* __restrict__ ratiog,
    bf16* __restrict__ Tg, bf16* __restrict__ Mg) {
    const int u = blockIdx.x;
    const int bh = u >> 5, nc = u & 31;
    const int t0 = nc * CK_;
    const int tid = threadIdx.x, wave = tid >> 6, lane = tid & 63;
    const int qd = lane >> 4, ln = lane & 15;
    __shared__ bf16 Kc[64 * 136], Qc[64 * 136];
    __shared__ float Af[64 * 65], Mf[64 * 65];
    __shared__ float cv[64], bv[64];
    const size_t kbase = ((size_t)bh * T_ + t0) * 128;
#pragma unroll
    for (int it = 0; it < 4; ++it) {
        int idx = it * 256 + tid;
        int row = idx >> 4, c8 = idx & 15;
        *(uint4*)(&Kc[row * 136 + c8 * 8]) = *(const uint4*)(kb + kbase + row * 128 + c8 * 8);
        *(uint4*)(&Qc[row * 136 + c8 * 8]) = *(const uint4*)(qb + kbase + row * 128 + c8 * 8);
    }
    // wave 0: g/beta prefix scan (independent of Kc/Qc)
    if (wave == 0) {
        float g = gbuf[(size_t)bh * T_ + t0 + lane];
        float beta = bbuf[(size_t)bh * T_ + t0 + lane];
        float c = g;
#pragma unroll
        for (int off = 1; off < 64; off <<= 1) {
            float tval = __shfl_up(c, off);
            if (lane >= off) c += tval;
        }
        float c63 = __shfl(c, 63);
        lamg[(size_t)u * 64 + lane] = __expf(c);
        ratiog[(size_t)u * 64 + lane] = __expf(c63 - c);
        cv[lane] = c; bv[lane] = beta;
    }
    __syncthreads();
    // MFMA quadrants into registers, then LDS f32
    floatx4 rA[4], rM[4];
#pragma unroll
    for (int nt = 0; nt < 4; ++nt) {
        floatx4 accA = {0.f, 0.f, 0.f, 0.f}, accM = {0.f, 0.f, 0.f, 0.f};
#pragma unroll
        for (int kk = 0; kk < 4; ++kk) {
            bf16x8 bfr = *(const bf16x8*)(&Kc[(nt * 16 + ln) * 136 + kk * 32 + qd * 8]);
            bf16x8 afK = *(const bf16x8*)(&Kc[(wave * 16 + ln) * 136 + kk * 32 + qd * 8]);
            bf16x8 afQ = *(const bf16x8*)(&Qc[(wave * 16 + ln) * 136 + kk * 32 + qd * 8]);
            accA = __builtin_amdgcn_mfma_f32_16x16x32_bf16(afK, bfr, accA, 0, 0, 0);
            accM = __builtin_amdgcn_mfma_f32_16x16x32_bf16(afQ, bfr, accM, 0, 0, 0);
        }
        rA[nt] = accA; rM[nt] = accM;
    }
#pragma unroll
    for (int nt = 0; nt < 4; ++nt)
#pragma unroll
        for (int ii = 0; ii < 4; ++ii) {
            int i = wave * 16 + qd * 4 + ii, j = nt * 16 + ln;
            Af[i * 65 + j] = rA[nt][ii];
            Mf[i * 65 + j] = rM[nt][ii];
        }
    __syncthreads();
    // L-fill in place (256-wide)
#pragma unroll
    for (int r = 0; r < 16; ++r) {
        const int i = wave * 16 + r;
        float a = Af[i * 65 + lane];
        Af[i * 65 + lane] = (lane < i) ? bv[i] * __expf(cv[i] - cv[lane]) * a : 0.f;
    }
    __syncthreads();
    if (wave == 0) {
        // triangular solve: T = (I+L)^{-1}, lane = column
        float t[64];
#pragma unroll
        for (int i = 0; i < 64; ++i) t[i] = (i == lane) ? 1.f : 0.f;
#pragma unroll
        for (int j = 0; j < 63; ++j) {
#pragma unroll
            for (int i = j + 1; i < 64; ++i)
                t[i] -= Af[i * 65 + j] * t[j];
        }
#pragma unroll
        for (int i = 0; i < 64; ++i)
            Tg[(size_t)u * 4096 + i * 64 + lane] = (bf16)t[i];
    } else {
        // Mg mask+store: rows i = wave-1, wave-1+3, ...
        for (int i = wave - 1; i < 64; i += 3) {
            float m = Mf[i * 65 + lane];
            float mij = (lane <= i) ? __expf(cv[i] - cv[lane]) * m : 0.f;
            Mg[(size_t)u * 4096 + i * 64 + lane] = (bf16)mij;
        }
    }
}

// ---------------- sequential chunk loop ----------------
// 256 blocks = 8 v-splits (dv=16) x 32 bh. kTb vector loads for stage-5
// A-fragments; Q@S hoisted into stage 1. __syncthreads barriers (the
// lgkmcnt-only variant measured +8us in r9 -> reverted).
struct Pref {
    uint4 t2[2], m2[2];
    bf16x8 kf[4], qf[4];
    bf16x8 ktf[2][2];   // transposed K fragments for stage 5
    float rrv[4], vv[4], lam[4], bet[4], lamlast;
};

__device__ __forceinline__ void load_pref(
    Pref& p, int u, int t0, size_t kbase, int tid, int wave, int ln, int qd,
    int bh, int vbase,
    const bf16* __restrict__ qb, const bf16* __restrict__ kb, const bf16* __restrict__ vb,
    const bf16* __restrict__ kTb,
    const bf16* __restrict__ Tg, const bf16* __restrict__ Mg,
    const float* __restrict__ lamg, const float* __restrict__ ratiog,
    const float* __restrict__ bbuf) {
#pragma unroll
    for (int it = 0; it < 2; ++it) {
        int idx = it * 256 + tid;
        int row = idx >> 3, c8 = idx & 7;
        p.t2[it] = *(const uint4*)(Tg + (size_t)u * 4096 + row * 64 + c8 * 8);
        p.m2[it] = *(const uint4*)(Mg + (size_t)u * 4096 + row * 64 + c8 * 8);
    }
    const size_t rowoff = kbase + (size_t)(wave * 16 + ln) * 128;
#pragma unroll
    for (int kk = 0; kk < 4; ++kk) {
        p.kf[kk] = *(const bf16x8*)(kb + rowoff + kk * 32 + qd * 8);
        p.qf[kk] = *(const bf16x8*)(qb + rowoff + kk * 32 + qd * 8);
    }
    const int i0 = wave * 16 + qd * 4;
#pragma unroll
    for (int ii = 0; ii < 4; ++ii) {
        p.vv[ii]  = (float)vb[kbase + (size_t)(i0 + ii) * 128 + vbase + ln];
        p.lam[ii] = lamg[(size_t)u * 64 + i0 + ii];
        p.bet[ii] = bbuf[(size_t)bh * T_ + t0 + i0 + ii];
        p.rrv[ii] = ratiog[(size_t)u * 64 + i0 + ii];
    }
    p.lamlast = lamg[(size_t)u * 64 + 63];
    // transposed-K fragments: coalesced bf16x8 from kTb[bh][kd][t]
#pragma unroll
    for (int mt = 0; mt < 2; ++mt) {
        const int kd = (wave * 2 + mt) * 16 + ln;
        const bf16* kt_row = kTb + ((size_t)bh * 128 + kd) * T_ + t0;
#pragma unroll
        for (int kk2 = 0; kk2 < 2; ++kk2)
            p.ktf[mt][kk2] = *(const bf16x8*)(kt_row + kk2 * 32 + qd * 8);
    }
}

__global__ __launch_bounds__(256) void seq_kernel(
    const bf16* __restrict__ qb, const bf16* __restrict__ kb, const bf16* __restrict__ vb,
    const bf16* __restrict__ kTb,
    const bf16* __restrict__ Tg, const bf16* __restrict__ Mg,
    const float* __restrict__ lamg, const float* __restrict__ ratiog,
    const float* __restrict__ bbuf, float* __restrict__ ob) {
    const int bh = blockIdx.x & 31;
    const int vs = blockIdx.x >> 5;
    const int vbase = vs * 16;
    const int tid = threadIdx.x;
    const int wave = tid >> 6, lane = tid & 63;
    const int qd = lane >> 4, ln = lane & 15;

    __shared__ bf16 Tt[64 * 72], Mm[64 * 72];
    __shared__ bf16 bT[16 * 72], Dt[16 * 72], Dtr[16 * 72];
    __shared__ bf16 Sbf[2][16 * 136];   // ping-pong bf16 S (B-operand layout)

    for (int idx = tid; idx < 2 * 16 * 136; idx += 256)
        (&Sbf[0][0])[idx] = (bf16)0.f;

    // f32 master S in registers: lane (wave,ln,qd) owns S[k=(wave*2+mt)*16+qd*4+ii][v=ln]
    floatx4 Sreg[2] = { floatx4{0.f, 0.f, 0.f, 0.f}, floatx4{0.f, 0.f, 0.f, 0.f} };

    auto chunk_body = [&](Pref& cur, Pref& nxt, int nc, bf16* Srd, bf16* Swr) {
        const int t0 = nc * CK_;
        const size_t kbase = ((size_t)bh * T_ + t0) * 128;

        // stage LDS from cur regs (Tt/Mm only consumed after B1 -> no barrier here)
#pragma unroll
        for (int it = 0; it < 2; ++it) {
            int idx = it * 256 + tid;
            int row = idx >> 3, c8 = idx & 7;
            *(uint4*)(&Tt[row * 72 + c8 * 8]) = cur.t2[it];
            *(uint4*)(&Mm[row * 72 + c8 * 8]) = cur.m2[it];
        }

        // prefetch next chunk into regs (consumed one chunk later)
        {
            const int ncn = (nc + 1 < NC_) ? nc + 1 : nc;
            load_pref(nxt, bh * NC_ + ncn, ncn * CK_, ((size_t)bh * T_ + (size_t)ncn * CK_) * 128,
                      tid, wave, ln, qd, bh, vbase, qb, kb, vb, kTb, Tg, Mg, lamg, ratiog, bbuf);
        }

        // stage 1: KS = K @ S  and  QS = Q @ S (shared Srd reads; QS consumed in stage 4)
        floatx4 ks = {0.f, 0.f, 0.f, 0.f};
        floatx4 qs = {0.f, 0.f, 0.f, 0.f};
#pragma unroll
        for (int kk = 0; kk < 4; ++kk) {
            bf16x8 bf = *(const bf16x8*)(&Srd[ln * 136 + kk * 32 + qd * 8]);
            ks = __builtin_amdgcn_mfma_f32_16x16x32_bf16(cur.kf[kk], bf, ks, 0, 0, 0);
            qs = __builtin_amdgcn_mfma_f32_16x16x32_bf16(cur.qf[kk], bf, qs, 0, 0, 0);
        }
        // stage 2: b = beta*(V - lam*KS) -> bT[v][i]
        {
            const int i0 = wave * 16 + qd * 4;
            bf16x4 bw;
#pragma unroll
            for (int ii = 0; ii < 4; ++ii)
                bw[ii] = (bf16)(cur.bet[ii] * (cur.vv[ii] - cur.lam[ii] * ks[ii]));
            *(bf16x4*)(&bT[ln * 72 + i0]) = bw;
        }
        __syncthreads();  // B1

        // stage 3: D = T @ b -> Dt[v][i]; Dtr = D*rr
        {
            floatx4 acc = {0.f, 0.f, 0.f, 0.f};
#pragma unroll
            for (int kk = 0; kk < 2; ++kk) {
                bf16x8 af = *(const bf16x8*)(&Tt[(wave * 16 + ln) * 72 + kk * 32 + qd * 8]);
                bf16x8 bf = *(const bf16x8*)(&bT[ln * 72 + kk * 32 + qd * 8]);
                acc = __builtin_amdgcn_mfma_f32_16x16x32_bf16(af, bf, acc, 0, 0, 0);
            }
            const int i0 = wave * 16 + qd * 4;
            bf16x4 dw = { (bf16)acc[0], (bf16)acc[1], (bf16)acc[2], (bf16)acc[3] };
            *(bf16x4*)(&Dt[ln * 72 + i0]) = dw;
            bf16x4 dwr = { (bf16)(acc[0] * cur.rrv[0]), (bf16)(acc[1] * cur.rrv[1]),
                           (bf16)(acc[2] * cur.rrv[2]), (bf16)(acc[3] * cur.rrv[3]) };
            *(bf16x4*)(&Dtr[ln * 72 + i0]) = dwr;
        }
        __syncthreads();  // B2

        // stage 4: O = lam ⊙ QS + M@D -> global
        {
            floatx4 o;
#pragma unroll
            for (int ii = 0; ii < 4; ++ii) o[ii] = qs[ii] * cur.lam[ii];
#pragma unroll
            for (int kk = 0; kk < 2; ++kk) {
                bf16x8 af = *(const bf16x8*)(&Mm[(wave * 16 + ln) * 72 + kk * 32 + qd * 8]);
                bf16x8 bf = *(const bf16x8*)(&Dt[ln * 72 + kk * 32 + qd * 8]);
                o = __builtin_amdgcn_mfma_f32_16x16x32_bf16(af, bf, o, 0, 0, 0);
            }
            const int i0 = wave * 16 + qd * 4;
#pragma unroll
            for (int ii = 0; ii < 4; ++ii)
                ob[kbase + (size_t)(i0 + ii) * 128 + vbase + ln] = o[ii];
        }
        // stage 5: S = lamlast*S + K^T @ (rr⊙D); f32 in regs, bf16 -> Swr
#pragma unroll
        for (int mt = 0; mt < 2; ++mt) {
            const int kt = wave * 2 + mt;
            floatx4 acc = {0.f, 0.f, 0.f, 0.f};
#pragma unroll
            for (int kk = 0; kk < 2; ++kk) {
                bf16x8 bf = *(const bf16x8*)(&Dtr[ln * 72 + kk * 32 + qd * 8]);
                acc = __builtin_amdgcn_mfma_f32_16x16x32_bf16(cur.ktf[mt][kk], bf, acc, 0, 0, 0);
            }
            floatx4 sold = Sreg[mt];
#pragma unroll
            for (int ii = 0; ii < 4; ++ii) sold[ii] = sold[ii] * cur.lamlast + acc[ii];
            Sreg[mt] = sold;
            bf16x4 sb4 = { (bf16)sold[0], (bf16)sold[1], (bf16)sold[2], (bf16)sold[3] };
            *(bf16x4*)(&Swr[ln * 136 + kt * 16 + qd * 4]) = sb4;
        }
        __syncthreads();  // B3
    };

    Pref pA, pB;
    load_pref(pA, bh * NC_, 0, (size_t)bh * T_ * 128, tid, wave, ln, qd, bh, vbase,
              qb, kb, vb, kTb, Tg, Mg, lamg, ratiog, bbuf);
    __syncthreads();

#pragma unroll 1
    for (int nc2 = 0; nc2 < NC_; nc2 += 2) {
        chunk_body(pA, pB, nc2,     &Sbf[0][0], &Sbf[1][0]);
        chunk_body(pB, pA, nc2 + 1, &Sbf[1][0], &Sbf[0][0]);
    }
}

// ---------------- o = o*silu(z); RMSNorm over DV; -> bf16 ----------------
// 4 heads per 256-thread block (head = one 64-lane wave).
__global__ __launch_bounds__(256) void gated_norm_kernel(
    const float* __restrict__ ob, const bf16* __restrict__ z,
    const float* __restrict__ nw, bf16* __restrict__ onorm) {
    const int idx = blockIdx.x * 4 + (threadIdx.x >> 6);  // B*T*H
    const int h = idx & (H_ - 1);
    const int bt = idx >> 4;
    const int t = bt & (T_ - 1);
    const int b = bt >> 11;
    const int tid = threadIdx.x & 63;
    const size_t obase = (((size_t)(b * H_ + h)) * T_ + t) * 128;
    const size_t zbase = (size_t)bt * 2048 + (h << 7);
    float o1 = ob[obase + tid], o2 = ob[obase + tid + 64];
    const float z1 = (float)z[zbase + tid], z2 = (float)z[zbase + tid + 64];
    o1 *= z1 / (1.f + __expf(-z1));
    o2 *= z2 / (1.f + __expf(-z2));
    float ss = o1 * o1 + o2 * o2;
#pragma unroll
    for (int o = 1; o < 64; o <<= 1) ss += __shfl_xor(ss, o);
    const float scale = rsqrtf(ss * (1.f / 128.f) + 1e-6f);
    onorm[zbase + tid]      = (bf16)(o1 * scale * nw[tid]);
    onorm[zbase + tid + 64] = (bf16)(o2 * scale * nw[tid + 64]);
}

extern "C" void kernel_launch(void* const* d_in, const int* in_sizes, int n_in,
                              void* d_out, int out_size, void* d_ws, size_t ws_size,
                              hipStream_t stream) {
    const float* X    = (const float*)d_in[0];
    const float* Wqkv = (const float*)d_in[1];
    const float* cw   = (const float*)d_in[2];
    const float* Wz   = (const float*)d_in[3];
    const float* Wb   = (const float*)d_in[4];
    const float* Wa   = (const float*)d_in[5];
    const float* dtb  = (const float*)d_in[6];
    const float* Alog = (const float*)d_in[7];
    const float* nw   = (const float*)d_in[8];
    const float* Wout = (const float*)d_in[9];
    float* out = (float*)d_out;

    char* ws = (char*)d_ws;
    size_t off = 0;
    auto alloc = [&](size_t bytes) -> char* {
        char* p = ws + off;
        off += (bytes + 255) & ~(size_t)255;
        return p;
    };
    bf16*  Xb      = (bf16*)alloc((size_t)B_ * T_ * D_ * 2);
    // Wcat = [Wqkv^T (6144 rows) ; Wz^T (2048 rows)] -> 8192 x 2048 bf16
    char*  wcat_p  = alloc((size_t)8192 * 2048 * 2);
    bf16*  Wcat    = (bf16*)wcat_p;
    bf16*  Woutt   = (bf16*)alloc((size_t)D_ * D_ * 2);
    bf16*  Wba     = (bf16*)alloc((size_t)32 * 2048 * 2);
    char*  mixed_p = alloc((size_t)B_ * T_ * CONV_DIM_ * 2);
    bf16*  mixedb  = (bf16*)mixed_p;
    bf16*  zb      = (bf16*)alloc((size_t)B_ * T_ * D_ * 2);
    bf16*  kbuf    = (bf16*)alloc((size_t)B_ * T_ * D_ * 2);
    bf16*  vbuf    = (bf16*)alloc((size_t)B_ * T_ * D_ * 2);
    bf16*  kTb     = (bf16*)alloc((size_t)B_ * H_ * 128 * T_ * 2);
    float* gbuf    = (float*)alloc((size_t)B_ * T_ * H_ * 4);
    float* bbuf    = (float*)alloc((size_t)B_ * T_ * H_ * 4);
    bf16*  Tg      = (bf16*)alloc((size_t)1024 * 4096 * 2);
    bf16*  Mg      = (bf16*)alloc((size_t)1024 * 4096 * 2);
    float* lamg    = (float*)alloc((size_t)1024 * 64 * 4);
    float* ratiog  = (float*)alloc((size_t)1024 * 64 * 4);
    // aliases (stream-order safe):
    bf16*  qbuf    = (bf16*)wcat_p;
    float* obuf    = (float*)mixed_p;
    bf16*  onorm   = (bf16*)Xb;

    cvt_bf16_kernel<<<dim3((B_ * T_ * D_ / 4 + 255) / 256), dim3(256), 0, stream>>>(X, Xb, B_ * T_ * D_ / 4);
    transpose_kernel<<<dim3(CONV_DIM_ / 32, D_ / 32), dim3(256), 0, stream>>>(Wqkv, Wcat, D_, CONV_DIM_);
    transpose_kernel<<<dim3(D_ / 32, D_ / 32), dim3(256), 0, stream>>>(Wz, Wcat + (size_t)CONV_DIM_ * D_, D_, D_);
    transpose_kernel<<<dim3(D_ / 32, D_ / 32), dim3(256), 0, stream>>>(Wout, Woutt, D_, D_);
    wba_cvt_kernel<<<dim3(128), dim3(256), 0, stream>>>(Wb, Wa, Wba);

    // fused QKV+Z projection: [4096 x 2048] @ [2048 x 8192]; cols<6144 -> mixed, else -> z
    gemm256_kernel<<<dim3(8192 / 256, B_ * T_ / 256), dim3(512), 0, stream>>>(
        Xb, Wcat, mixedb, zb, B_ * T_, 8192, D_, CONV_DIM_, CONV_DIM_, D_);

    gbeta_mfma_kernel<<<dim3(256), dim3(64), 0, stream>>>(Xb, Wba, dtb, Alog, gbuf, bbuf);
    conv_silu_kernel<<<dim3(CONV_DIM_ / 2048, B_ * T_), dim3(256), 0, stream>>>(mixedb, cw, qbuf, kbuf, vbuf);

    kt_transpose_kernel<<<dim3(128 / 32, T_ / 32, B_ * H_), dim3(256), 0, stream>>>(kbuf, kTb);
    qkkt_prep_kernel<<<dim3(1024), dim3(256), 0, stream>>>(qbuf, kbuf, gbuf, bbuf, lamg, ratiog, Tg, Mg);
    seq_kernel<<<dim3(256), dim3(256), 0, stream>>>(qbuf, kbuf, vbuf, kTb, Tg, Mg, lamg, ratiog, bbuf, obuf);

    gated_norm_kernel<<<dim3(B_ * T_ * H_ / 4), dim3(256), 0, stream>>>(obuf, zb, nw, onorm);

    gemm_kernel<float><<<dim3(D_ / 128, B_ * T_ / 128), dim3(256), 0, stream>>>(
        onorm, Woutt, out, B_ * T_, D_, D_);
}

// Round 12
// 558.394 us; speedup vs baseline: 1.0440x; 1.0090x over previous
//
#include <hip/hip_runtime.h>

#define B_ 2
#define T_ 2048
#define D_ 2048
#define H_ 16
#define CONV_DIM_ 6144
#define NC_ 32   // chunks per sequence
#define CK_ 64   // chunk length

typedef __bf16 bf16;
typedef bf16 bf16x8 __attribute__((ext_vector_type(8)));
typedef bf16 bf16x4 __attribute__((ext_vector_type(4)));
typedef float floatx4 __attribute__((ext_vector_type(4)));

// async global->LDS 16B per lane: dest = wave-uniform base + lane*16
__device__ __forceinline__ void async_copy16(bf16* lds, const bf16* g) {
    auto* g1 = (const __attribute__((address_space(1))) unsigned int*)g;
    auto* l3 = (__attribute__((address_space(3))) unsigned int*)lds;
    __builtin_amdgcn_global_load_lds(g1, l3, 16, 0, 0);
}

// ---------------- fused: f32->bf16 cvt (blocks 0..8191) + Wba pack (8192..8319) ----------------
__global__ __launch_bounds__(256) void cvt_wba_kernel(
    const float* __restrict__ in, bf16* __restrict__ out, int n4,
    const float* __restrict__ Wb, const float* __restrict__ Wa, bf16* __restrict__ Wba) {
    if (blockIdx.x < 8192) {
        int i = blockIdx.x * 256 + threadIdx.x;
        if (i < n4) {
            float4 v = ((const float4*)in)[i];
            bf16x4 o = { (bf16)v.x, (bf16)v.y, (bf16)v.z, (bf16)v.w };
            *(bf16x4*)(out + 4 * (size_t)i) = o;
        }
    } else {
        int idx = (blockIdx.x - 8192) * 256 + threadIdx.x;  // 32768
        int d = idx >> 4, h = idx & 15;
        Wba[(size_t)h * 2048 + d]        = (bf16)Wb[idx];
        Wba[(size_t)(h + 16) * 2048 + d] = (bf16)Wa[idx];
    }
}

// ---------------- fused 3x transpose f32 [2048,Cn] -> bf16 [Cn,2048] ----------------
// flat grid: [0,12288) Wqkv->Wcat ; [12288,16384) Wz->Wcat+6144*2048 ; [16384,20480) Wout->Woutt
__global__ __launch_bounds__(256) void transpose3_kernel(
    const float* __restrict__ Wqkv, const float* __restrict__ Wz, const float* __restrict__ Wout,
    bf16* __restrict__ Wcat, bf16* __restrict__ Woutt) {
    __shared__ float tile[32][33];
    const int bid = blockIdx.x;
    const float* in; bf16* out; int Cn, bx, by;
    if (bid < 12288)       { in = Wqkv; out = Wcat;                         Cn = 6144; bx = bid % 192;  by = bid / 192; }
    else if (bid < 16384)  { int b2 = bid - 12288; in = Wz;   out = Wcat + (size_t)CONV_DIM_ * D_; Cn = 2048; bx = b2 & 63; by = b2 >> 6; }
    else                   { int b3 = bid - 16384; in = Wout; out = Woutt;  Cn = 2048; bx = b3 & 63; by = b3 >> 6; }
    const int c0 = bx << 5, r0 = by << 5;
    const int tx = threadIdx.x & 31, ty = threadIdx.x >> 5;
#pragma unroll
    for (int i = 0; i < 4; ++i) {
        int r = ty + (i << 3);
        tile[r][tx] = in[(size_t)(r0 + r) * Cn + c0 + tx];
    }
    __syncthreads();
#pragma unroll
    for (int i = 0; i < 4; ++i) {
        int cc = ty + (i << 3);
        out[(size_t)(c0 + cc) * D_ + r0 + tx] = (bf16)tile[tx][cc];
    }
}

// ---------------- bf16 MFMA GEMM: A[M,K] x Bt[N,K] -> C[M,N] ----------------
// 128x128 tile, 4 waves, BK=64, XOR-swizzled LDS, global_load_lds staging (m97).
template <typename OutT>
__global__ __launch_bounds__(256) void gemm_kernel(
    const bf16* __restrict__ A, const bf16* __restrict__ Bt, OutT* __restrict__ C,
    int M, int N, int K) {
    __shared__ bf16 As[128 * 64];
    __shared__ bf16 Bs[128 * 64];
    const int tid = threadIdx.x;
    const int m0 = blockIdx.y << 7;
    const int n0 = blockIdx.x << 7;
    const int wave = tid >> 6, lane = tid & 63;
    const int wm = (wave >> 1) << 6, wn = (wave & 1) << 6;
    const int lrow = lane & 15, quad = lane >> 4;
    const int rl = lane >> 3;
    const int c8s = (lane & 7) ^ (rl & 7);

    floatx4 acc[4][4];
#pragma unroll
    for (int mt = 0; mt < 4; ++mt)
#pragma unroll
        for (int nt = 0; nt < 4; ++nt)
            acc[mt][nt] = floatx4{0.f, 0.f, 0.f, 0.f};

    for (int k0 = 0; k0 < K; k0 += 64) {
        __syncthreads();
#pragma unroll
        for (int i = 0; i < 4; ++i) {
            const int slot = wave * 4 + i;           // 16 slots of 8 rows
            const int r = slot * 8 + rl;
            async_copy16(&As[slot * 512], A + (size_t)(m0 + r) * K + k0 + c8s * 8);
            async_copy16(&Bs[slot * 512], Bt + (size_t)(n0 + r) * K + k0 + c8s * 8);
        }
        __syncthreads();
#pragma unroll
        for (int kk = 0; kk < 64; kk += 32) {
            const int sw = (((kk >> 3) + quad) ^ (lrow & 7)) << 3;
            bf16x8 af[4], bfr[4];
#pragma unroll
            for (int mt = 0; mt < 4; ++mt) {
                af[mt]  = *(const bf16x8*)(&As[((wm + (mt << 4) + lrow) << 6) + sw]);
                bfr[mt] = *(const bf16x8*)(&Bs[((wn + (mt << 4) + lrow) << 6) + sw]);
            }
#pragma unroll
            for (int mt = 0; mt < 4; ++mt)
#pragma unroll
                for (int nt = 0; nt < 4; ++nt)
                    acc[mt][nt] = __builtin_amdgcn_mfma_f32_16x16x32_bf16(af[mt], bfr[nt], acc[mt][nt], 0, 0, 0);
        }
    }
#pragma unroll
    for (int mt = 0; mt < 4; ++mt)
#pragma unroll
        for (int nt = 0; nt < 4; ++nt) {
            const int col = n0 + wn + (nt << 4) + lrow;
            const int rowb = m0 + wm + (mt << 4) + (quad << 2);
#pragma unroll
            for (int i2 = 0; i2 < 4; ++i2)
                C[(size_t)(rowb + i2) * N + col] = (OutT)acc[mt][nt][i2];
        }
}

// ---------------- 256x256-tile bf16 GEMM, 8 waves, 8-phase counted-vmcnt pipeline ----------------
// Frozen at ~945 TF / 40% MfmaUtil (2 schedule rewrites no-delta -> stop rule).
__global__ __launch_bounds__(512, 2) void gemm256_kernel(
    const bf16* __restrict__ A, const bf16* __restrict__ Bt,
    bf16* __restrict__ C0, bf16* __restrict__ C1,
    int M, int Ncat, int K, int split, int ld0, int ld1) {
    __shared__ bf16 As[4][256 * 32];
    __shared__ bf16 Bs[4][256 * 32];
    const int tid = threadIdx.x;
    const int wave = tid >> 6, lane = tid & 63;
    const int quad = lane >> 4, lrow = lane & 15;
    const int wm = (wave >> 2) << 7;   // 0 / 128
    const int wn = (wave & 3) << 6;    // 0 / 64 / 128 / 192
    const int m0 = blockIdx.y << 8, n0 = blockIdx.x << 8;

    const bf16* gA[2];
    const bf16* gB[2];
#pragma unroll
    for (int i = 0; i < 2; ++i) {
        const int q = wave * 2 + i;
        const int u = (lane & 7) ^ (lane >> 3);          // pre-swizzle unit
        const int row = (q * 8 + (lane >> 3)) * 2 + (u >> 2);
        const int col = (u & 3) * 8;
        gA[i] = A  + (size_t)(m0 + row) * K + col;
        gB[i] = Bt + (size_t)(n0 + row) * K + col;
    }

    auto loff = [](int row, int qd) -> int {
        return ((row >> 1) << 6) + (((((row & 1) << 2) | qd) ^ ((row >> 1) & 7)) << 3);
    };

    floatx4 acc[8][4];
#pragma unroll
    for (int mt = 0; mt < 8; ++mt)
#pragma unroll
        for (int nt = 0; nt < 4; ++nt)
            acc[mt][nt] = floatx4{0.f, 0.f, 0.f, 0.f};

    const int KT = K >> 5;   // K=32 sub-tiles

#pragma unroll
    for (int t = 0; t < 3; ++t) {
        async_copy16(&As[t][(wave * 2 + 0) * 512], gA[0] + t * 32);
        async_copy16(&As[t][(wave * 2 + 1) * 512], gA[1] + t * 32);
        async_copy16(&Bs[t][(wave * 2 + 0) * 512], gB[0] + t * 32);
        async_copy16(&Bs[t][(wave * 2 + 1) * 512], gB[1] + t * 32);
    }
    asm volatile("s_waitcnt vmcnt(8)" ::: "memory");
    __builtin_amdgcn_s_barrier();

    for (int t = 0; t < KT; ++t) {
        const int b = t & 3;
        const bf16* as = &As[b][0];
        const bf16* bs = &Bs[b][0];
        // ---------------- phase A (mh = 0) ----------------
        bf16x8 bfr[4], af[4];
#pragma unroll
        for (int nt = 0; nt < 4; ++nt)
            bfr[nt] = *(const bf16x8*)(bs + loff(wn + nt * 16 + lrow, quad));
#pragma unroll
        for (int mt = 0; mt < 4; ++mt)
            af[mt] = *(const bf16x8*)(as + loff(wm + mt * 16 + lrow, quad));
        if (t + 2 < KT)       asm volatile("s_waitcnt vmcnt(4)" ::: "memory");
        else if (t + 2 == KT) asm volatile("s_waitcnt vmcnt(0)" ::: "memory");
        if (t + 3 < KT) {
            const int bn = (t + 3) & 3;
            async_copy16(&As[bn][(wave * 2 + 0) * 512], gA[0] + (t + 3) * 32);
            async_copy16(&As[bn][(wave * 2 + 1) * 512], gA[1] + (t + 3) * 32);
        }
        __builtin_amdgcn_s_barrier();
        asm volatile("s_waitcnt lgkmcnt(0)" ::: "memory");
        __builtin_amdgcn_sched_barrier(0);
        __builtin_amdgcn_s_setprio(1);
#pragma unroll
        for (int mt = 0; mt < 4; ++mt)
#pragma unroll
            for (int nt = 0; nt < 4; ++nt)
                acc[mt][nt] = __builtin_amdgcn_mfma_f32_16x16x32_bf16(
                    af[mt], bfr[nt], acc[mt][nt], 0, 0, 0);
        __builtin_amdgcn_s_setprio(0);
        __builtin_amdgcn_sched_barrier(0);
        __builtin_amdgcn_s_barrier();
        // ---------------- phase B (mh = 1) ----------------
#pragma unroll
        for (int mt = 0; mt < 4; ++mt)
            af[mt] = *(const bf16x8*)(as + loff(wm + 64 + mt * 16 + lrow, quad));
        if (t + 3 < KT) {
            const int bn = (t + 3) & 3;
            async_copy16(&Bs[bn][(wave * 2 + 0) * 512], gB[0] + (t + 3) * 32);
            async_copy16(&Bs[bn][(wave * 2 + 1) * 512], gB[1] + (t + 3) * 32);
        }
        __builtin_amdgcn_s_barrier();
        asm volatile("s_waitcnt lgkmcnt(0)" ::: "memory");
        __builtin_amdgcn_sched_barrier(0);
        __builtin_amdgcn_s_setprio(1);
#pragma unroll
        for (int mt = 0; mt < 4; ++mt)
#pragma unroll
            for (int nt = 0; nt < 4; ++nt)
                acc[4 + mt][nt] = __builtin_amdgcn_mfma_f32_16x16x32_bf16(
                    af[mt], bfr[nt], acc[4 + mt][nt], 0, 0, 0);
        __builtin_amdgcn_s_setprio(0);
        __builtin_amdgcn_sched_barrier(0);
        __builtin_amdgcn_s_barrier();
    }

    const bool second = (n0 >= split);
    bf16* Cp = second ? C1 : C0;
    const int ldc = second ? ld1 : ld0;
    const int nc0 = second ? n0 - split : n0;
#pragma unroll
    for (int mt = 0; mt < 8; ++mt)
#pragma unroll
        for (int nt = 0; nt < 4; ++nt) {
            const int col = nc0 + wn + nt * 16 + lrow;
            const int rowb = m0 + wm + mt * 16 + (quad << 2);
#pragma unroll
            for (int i2 = 0; i2 < 4; ++i2)
                Cp[(size_t)(rowb + i2) * ldc + col] = (bf16)acc[mt][nt][i2];
        }
}

// ---------------- fused: depthwise conv+silu+l2norm (blocks 0..12287) + beta/g MFMA (12288..12351) ----------------
__global__ __launch_bounds__(256) void conv_gbeta_kernel(
    const bf16* __restrict__ mixed, const float* __restrict__ cw,
    bf16* __restrict__ qb, bf16* __restrict__ kb, bf16* __restrict__ vb,
    const bf16* __restrict__ Xb, const bf16* __restrict__ Wba,
    const float* __restrict__ dtb, const float* __restrict__ Alog,
    float* __restrict__ gbuf, float* __restrict__ bbuf) {
    if (blockIdx.x < 12288) {
        // ---- conv+silu+split+l2norm: 8 channels/thread ----
        const int bt = blockIdx.x & (4096 - 1);
        const int cx = blockIdx.x >> 12;
        const int t = bt & (T_ - 1);
        const int b = bt >> 11;
        const int c0 = cx * 2048 + threadIdx.x * 8;
        const size_t base = (size_t)bt * CONV_DIM_ + c0;

        bf16x8 zz;
#pragma unroll
        for (int j = 0; j < 8; ++j) zz[j] = (bf16)0.f;
        const bf16x8 r3 = *(const bf16x8*)(mixed + base);
        const bf16x8 r2 = (t >= 1) ? *(const bf16x8*)(mixed + base - CONV_DIM_) : zz;
        const bf16x8 r1 = (t >= 2) ? *(const bf16x8*)(mixed + base - 2 * CONV_DIM_) : zz;
        const bf16x8 r0 = (t >= 3) ? *(const bf16x8*)(mixed + base - 3 * CONV_DIM_) : zz;

        const float4* cw4 = (const float4*)cw;
        float vals[8];
        float ss = 0.f;
#pragma unroll
        for (int j = 0; j < 8; ++j) {
            const float4 w = cw4[c0 + j];
            float acc = (float)r3[j] * w.w + (float)r2[j] * w.z +
                        (float)r1[j] * w.y + (float)r0[j] * w.x;
            const float sv = acc / (1.f + __expf(-acc));  // silu
            vals[j] = sv;
            ss += sv * sv;
        }

        if (c0 < 4096) {
#pragma unroll
            for (int o = 1; o < 16; o <<= 1) ss += __shfl_xor(ss, o);
            const float scale = rsqrtf(ss + 1e-6f);
            const bool isq = c0 < 2048;
            const float mul = isq ? scale * 0.08838834764831845f : scale;
            const int h = (c0 >> 7) & 15;
            const int d0 = c0 & 127;
            const size_t oidx = (((size_t)(b * H_ + h)) * T_ + t) * 128 + d0;
            bf16x8 o8;
#pragma unroll
            for (int j = 0; j < 8; ++j) o8[j] = (bf16)(vals[j] * mul);
            *(bf16x8*)((isq ? qb : kb) + oidx) = o8;
        } else {
            const int h = (c0 >> 7) & 15;
            const int d0 = c0 & 127;
            const size_t oidx = (((size_t)(b * H_ + h)) * T_ + t) * 128 + d0;
            bf16x8 o8;
#pragma unroll
            for (int j = 0; j < 8; ++j) o8[j] = (bf16)vals[j];
            *(bf16x8*)(vb + oidx) = o8;
        }
    } else {
        // ---- beta/g skinny MFMA: 64 blocks x 4 waves x 16 rows ----
        const int tid = threadIdx.x, wave = tid >> 6, lane = tid & 63;
        const int ln = lane & 15, qd = lane >> 4;
        const int m0 = (blockIdx.x - 12288) * 64 + wave * 16;
        floatx4 acc0 = {0.f, 0.f, 0.f, 0.f}, acc1 = {0.f, 0.f, 0.f, 0.f};
        const bf16* arow = Xb + (size_t)(m0 + ln) * 2048 + qd * 8;
        const bf16* b0 = Wba + (size_t)ln * 2048 + qd * 8;
        const bf16* b1 = Wba + (size_t)(16 + ln) * 2048 + qd * 8;
        for (int k = 0; k < 2048; k += 32) {
            bf16x8 af  = *(const bf16x8*)(arow + k);
            bf16x8 bf0 = *(const bf16x8*)(b0 + k);
            bf16x8 bf1 = *(const bf16x8*)(b1 + k);
            acc0 = __builtin_amdgcn_mfma_f32_16x16x32_bf16(af, bf0, acc0, 0, 0, 0);
            acc1 = __builtin_amdgcn_mfma_f32_16x16x32_bf16(af, bf1, acc1, 0, 0, 0);
        }
        const float dtbv = dtb[ln], al = __expf(Alog[ln]);
#pragma unroll
        for (int ii = 0; ii < 4; ++ii) {
            const int row = m0 + qd * 4 + ii;  // bt
            const int t = row & (T_ - 1), b = row >> 11;
            const size_t o = ((size_t)(b * H_ + ln)) * T_ + t;
            bbuf[o] = 1.f / (1.f + __expf(-acc0[ii]));
            const float xx = acc1[ii] + dtbv;
            const float sp = (xx > 15.f) ? xx : log1pf(__expf(xx));
            gbuf[o] = -al * sp;
        }
    }
}

// ---------------- fused precompute: KK^T + QK^T -> decay/T/M + kTb transpose ----------------
// The K chunk already sits in LDS (Kc) -> also emit the transposed K slice
// kTb[bh][d][t0..t0+63] here (replaces the standalone kt_transpose kernel and
// its full kbuf global round-trip).
__global__ __launch_bounds__(256) void qkkt_prep_kernel(
    const bf16* __restrict__ qb, const bf16* __restrict__ kb,
    const float* __restrict__ gbuf, const float* __restrict__ bbuf,
    float* __restrict__ lamg, float* __restrict__ ratiog,
    bf16* __restrict__ Tg, bf16* __restrict__ Mg, bf16* __restrict__ kTb) {
    const int u = blockIdx.x;
    const int bh = u >> 5, nc = u & 31;
    const int t0 = nc * CK_;
    const int tid = threadIdx.x, wave = tid >> 6, lane = tid & 63;
    const int qd = lane >> 4, ln = lane & 15;
    __shared__ bf16 Kc[64 * 136], Qc[64 * 136];
    __shared__ float Af[64 * 65], Mf[64 * 65];
    __shared__ float cv[64], bv[64];
    const size_t kbase = ((size_t)bh * T_ + t0) * 128;
#pragma unroll
    for (int it = 0; it < 4; ++it) {
        int idx = it * 256 + tid;
        int row = idx >> 4, c8 = idx & 15;
        *(uint4*)(&Kc[row * 136 + c8 * 8]) = *(const uint4*)(kb + kbase + row * 128 + c8 * 8);
        *(uint4*)(&Qc[row * 136 + c8 * 8]) = *(const uint4*)(qb + kbase + row * 128 + c8 * 8);
    }
    // wave 0: g/beta prefix scan (independent of Kc/Qc)
    if (wave == 0) {
        float g = gbuf[(size_t)bh * T_ + t0 + lane];
        float beta = bbuf[(size_t)bh * T_ + t0 + lane];
        float c = g;
#pragma unroll
        for (int off = 1; off < 64; off <<= 1) {
            float tval = __shfl_up(c, off);
            if (lane >= off) c += tval;
        }
        float c63 = __shfl(c, 63);
        lamg[(size_t)u * 64 + lane] = __expf(c);
        ratiog[(size_t)u * 64 + lane] = __expf(c63 - c);
        cv[lane] = c; bv[lane] = beta;
    }
    __syncthreads();
    // MFMA quadrants into registers, then LDS f32
    floatx4 rA[4], rM[4];
#pragma unroll
    for (int nt = 0; nt < 4; ++nt) {
        floatx4 accA = {0.f, 0.f, 0.f, 0.f}, accM = {0.f, 0.f, 0.f, 0.f};
#pragma unroll
        for (int kk = 0; kk < 4; ++kk) {
            bf16x8 bfr = *(const bf16x8*)(&Kc[(nt * 16 + ln) * 136 + kk * 32 + qd * 8]);
            bf16x8 afK = *(const bf16x8*)(&Kc[(wave * 16 + ln) * 136 + kk * 32 + qd * 8]);
            bf16x8 afQ = *(const bf16x8*)(&Qc[(wave * 16 + ln) * 136 + kk * 32 + qd * 8]);
            accA = __builtin_amdgcn_mfma_f32_16x16x32_bf16(afK, bfr, accA, 0, 0, 0);
            accM = __builtin_amdgcn_mfma_f32_16x16x32_bf16(afQ, bfr, accM, 0, 0, 0);
        }
        rA[nt] = accA; rM[nt] = accM;
    }
#pragma unroll
    for (int nt = 0; nt < 4; ++nt)
#pragma unroll
        for (int ii = 0; ii < 4; ++ii) {
            int i = wave * 16 + qd * 4 + ii, j = nt * 16 + ln;
            Af[i * 65 + j] = rA[nt][ii];
            Mf[i * 65 + j] = rM[nt][ii];
        }
    // kTb emit: Kc[t][d] -> kTb[(bh*128+d)*T + t0+t] (coalesced 128B per 64-lane group)
#pragma unroll
    for (int it = 0; it < 32; ++it) {
        int idx = it * 256 + tid;          // 0..8191
        int d = idx >> 6, tt = idx & 63;
        kTb[((size_t)bh * 128 + d) * T_ + t0 + tt] = Kc[tt * 136 + d];
    }
    __syncthreads();
    // L-fill in place (256-wide)
#pragma unroll
    for (int r = 0; r < 16; ++r) {
        const int i = wave * 16 + r;
        float a = Af[i * 65 + lane];
        Af[i * 65 + lane] = (lane < i) ? bv[i] * __expf(cv[i] - cv[lane]) * a : 0.f;
    }
    __syncthreads();
    if (wave == 0) {
        // triangular solve: T = (I+L)^{-1}, lane = column
        float t[64];
#pragma unroll
        for (int i = 0; i < 64; ++i) t[i] = (i == lane) ? 1.f : 0.f;
#pragma unroll
        for (int j = 0; j < 63; ++j) {
#pragma unroll
            for (int i = j + 1; i < 64; ++i)
                t[i] -= Af[i * 65 + j] * t[j];
        }
#pragma unroll
        for (int i = 0; i < 64; ++i)
            Tg[(size_t)u * 4096 + i * 64 + lane] = (bf16)t[i];
    } else {
        // Mg mask+store: rows i = wave-1, wave-1+3, ...
        for (int i = wave - 1; i < 64; i += 3) {
            float m = Mf[i * 65 + lane];
            float mij = (lane <= i) ? __expf(cv[i] - cv[lane]) * m : 0.f;
            Mg[(size_t)u * 4096 + i * 64 + lane] = (bf16)mij;
        }
    }
}

// ---------------- sequential chunk loop ----------------
// 256 blocks = 8 v-splits (dv=16) x 32 bh. kTb vector loads for stage-5
// A-fragments; Q@S hoisted into stage 1. __syncthreads barriers.
struct Pref {
    uint4 t2[2], m2[2];
    bf16x8 kf[4], qf[4];
    bf16x8 ktf[2][2];   // transposed K fragments for stage 5
    float rrv[4], vv[4], lam[4], bet[4], lamlast;
};

__device__ __forceinline__ void load_pref(
    Pref& p, int u, int t0, size_t kbase, int tid, int wave, int ln, int qd,
    int bh, int vbase,
    const bf16* __restrict__ qb, const bf16* __restrict__ kb, const bf16* __restrict__ vb,
    const bf16* __restrict__ kTb,
    const bf16* __restrict__ Tg, const bf16* __restrict__ Mg,
    const float* __restrict__ lamg, const float* __restrict__ ratiog,
    const float* __restrict__ bbuf) {
#pragma unroll
    for (int it = 0; it < 2; ++it) {
        int idx = it * 256 + tid;
        int row = idx >> 3, c8 = idx & 7;
        p.t2[it] = *(const uint4*)(Tg + (size_t)u * 4096 + row * 64 + c8 * 8);
        p.m2[it] = *(const uint4*)(Mg + (size_t)u * 4096 + row * 64 + c8 * 8);
    }
    const size_t rowoff = kbase + (size_t)(wave * 16 + ln) * 128;
#pragma unroll
    for (int kk = 0; kk < 4; ++kk) {
        p.kf[kk] = *(const bf16x8*)(kb + rowoff + kk * 32 + qd * 8);
        p.qf[kk] = *(const bf16x8*)(qb + rowoff + kk * 32 + qd * 8);
    }
    const int i0 = wave * 16 + qd * 4;
#pragma unroll
    for (int ii = 0; ii < 4; ++ii) {
        p.vv[ii]  = (float)vb[kbase + (size_t)(i0 + ii) * 128 + vbase + ln];
        p.lam[ii] = lamg[(size_t)u * 64 + i0 + ii];
        p.bet[ii] = bbuf[(size_t)bh * T_ + t0 + i0 + ii];
        p.rrv[ii] = ratiog[(size_t)u * 64 + i0 + ii];
    }
    p.lamlast = lamg[(size_t)u * 64 + 63];
    // transposed-K fragments: coalesced bf16x8 from kTb[bh][kd][t]
#pragma unroll
    for (int mt = 0; mt < 2; ++mt) {
        const int kd = (wave * 2 + mt) * 16 + ln;
        const bf16* kt_row = kTb + ((size_t)bh * 128 + kd) * T_ + t0;
#pragma unroll
        for (int kk2 = 0; kk2 < 2; ++kk2)
            p.ktf[mt][kk2] = *(const bf16x8*)(kt_row + kk2 * 32 + qd * 8);
    }
}

__global__ __launch_bounds__(256) void seq_kernel(
    const bf16* __restrict__ qb, const bf16* __restrict__ kb, const bf16* __restrict__ vb,
    const bf16* __restrict__ kTb,
    const bf16* __restrict__ Tg, const bf16* __restrict__ Mg,
    const float* __restrict__ lamg, const float* __restrict__ ratiog,
    const float* __restrict__ bbuf, float* __restrict__ ob) {
    const int bh = blockIdx.x & 31;
    const int vs = blockIdx.x >> 5;
    const int vbase = vs * 16;
    const int tid = threadIdx.x;
    const int wave = tid >> 6, lane = tid & 63;
    const int qd = lane >> 4, ln = lane & 15;

    __shared__ bf16 Tt[64 * 72], Mm[64 * 72];
    __shared__ bf16 bT[16 * 72], Dt[16 * 72], Dtr[16 * 72];
    __shared__ bf16 Sbf[2][16 * 136];   // ping-pong bf16 S (B-operand layout)

    for (int idx = tid; idx < 2 * 16 * 136; idx += 256)
        (&Sbf[0][0])[idx] = (bf16)0.f;

    // f32 master S in registers: lane (wave,ln,qd) owns S[k=(wave*2+mt)*16+qd*4+ii][v=ln]
    floatx4 Sreg[2] = { floatx4{0.f, 0.f, 0.f, 0.f}, floatx4{0.f, 0.f, 0.f, 0.f} };

    auto chunk_body = [&](Pref& cur, Pref& nxt, int nc, bf16* Srd, bf16* Swr) {
        const int t0 = nc * CK_;
        const size_t kbase = ((size_t)bh * T_ + t0) * 128;

        // stage LDS from cur regs (Tt/Mm only consumed after B1 -> no barrier here)
#pragma unroll
        for (int it = 0; it < 2; ++it) {
            int idx = it * 256 + tid;
            int row = idx >> 3, c8 = idx & 7;
            *(uint4*)(&Tt[row * 72 + c8 * 8]) = cur.t2[it];
            *(uint4*)(&Mm[row * 72 + c8 * 8]) = cur.m2[it];
        }

        // prefetch next chunk into regs (consumed one chunk later)
        {
            const int ncn = (nc + 1 < NC_) ? nc + 1 : nc;
            load_pref(nxt, bh * NC_ + ncn, ncn * CK_, ((size_t)bh * T_ + (size_t)ncn * CK_) * 128,
                      tid, wave, ln, qd, bh, vbase, qb, kb, vb, kTb, Tg, Mg, lamg, ratiog, bbuf);
        }

        // stage 1: KS = K @ S  and  QS = Q @ S (shared Srd reads; QS consumed in stage 4)
        floatx4 ks = {0.f, 0.f, 0.f, 0.f};
        floatx4 qs = {0.f, 0.f, 0.f, 0.f};
#pragma unroll
        for (int kk = 0; kk < 4; ++kk) {
            bf16x8 bf = *(const bf16x8*)(&Srd[ln * 136 + kk * 32 + qd * 8]);
            ks = __builtin_amdgcn_mfma_f32_16x16x32_bf16(cur.kf[kk], bf, ks, 0, 0, 0);
            qs = __builtin_amdgcn_mfma_f32_16x16x32_bf16(cur.qf[kk], bf, qs, 0, 0, 0);
        }
        // stage 2: b = beta*(V - lam*KS) -> bT[v][i]
        {
            const int i0 = wave * 16 + qd * 4;
            bf16x4 bw;
#pragma unroll
            for (int ii = 0; ii < 4; ++ii)
                bw[ii] = (bf16)(cur.bet[ii] * (cur.vv[ii] - cur.lam[ii] * ks[ii]));
            *(bf16x4*)(&bT[ln * 72 + i0]) = bw;
        }
        __syncthreads();  // B1

        // stage 3: D = T @ b -> Dt[v][i]; Dtr = D*rr
        {
            floatx4 acc = {0.f, 0.f, 0.f, 0.f};
#pragma unroll
            for (int kk = 0; kk < 2; ++kk) {
                bf16x8 af = *(const bf16x8*)(&Tt[(wave * 16 + ln) * 72 + kk * 32 + qd * 8]);
                bf16x8 bf = *(const bf16x8*)(&bT[ln * 72 + kk * 32 + qd * 8]);
                acc = __builtin_amdgcn_mfma_f32_16x16x32_bf16(af, bf, acc, 0, 0, 0);
            }
            const int i0 = wave * 16 + qd * 4;
            bf16x4 dw = { (bf16)acc[0], (bf16)acc[1], (bf16)acc[2], (bf16)acc[3] };
            *(bf16x4*)(&Dt[ln * 72 + i0]) = dw;
            bf16x4 dwr = { (bf16)(acc[0] * cur.rrv[0]), (bf16)(acc[1] * cur.rrv[1]),
                           (bf16)(acc[2] * cur.rrv[2]), (bf16)(acc[3] * cur.rrv[3]) };
            *(bf16x4*)(&Dtr[ln * 72 + i0]) = dwr;
        }
        __syncthreads();  // B2

        // stage 4: O = lam ⊙ QS + M@D -> global
        {
            floatx4 o;
#pragma unroll
            for (int ii = 0; ii < 4; ++ii) o[ii] = qs[ii] * cur.lam[ii];
#pragma unroll
            for (int kk = 0; kk < 2; ++kk) {
                bf16x8 af = *(const bf16x8*)(&Mm[(wave * 16 + ln) * 72 + kk * 32 + qd * 8]);
                bf16x8 bf = *(const bf16x8*)(&Dt[ln * 72 + kk * 32 + qd * 8]);
                o = __builtin_amdgcn_mfma_f32_16x16x32_bf16(af, bf, o, 0, 0, 0);
            }
            const int i0 = wave * 16 + qd * 4;
#pragma unroll
            for (int ii = 0; ii < 4; ++ii)
                ob[kbase + (size_t)(i0 + ii) * 128 + vbase + ln] = o[ii];
        }
        // stage 5: S = lamlast*S + K^T @ (rr⊙D); f32 in regs, bf16 -> Swr
#pragma unroll
        for (int mt = 0; mt < 2; ++mt) {
            const int kt = wave * 2 + mt;
            floatx4 acc = {0.f, 0.f, 0.f, 0.f};
#pragma unroll
            for (int kk = 0; kk < 2; ++kk) {
                bf16x8 bf = *(const bf16x8*)(&Dtr[ln * 72 + kk * 32 + qd * 8]);
                acc = __builtin_amdgcn_mfma_f32_16x16x32_bf16(cur.ktf[mt][kk], bf, acc, 0, 0, 0);
            }
            floatx4 sold = Sreg[mt];
#pragma unroll
            for (int ii = 0; ii < 4; ++ii) sold[ii] = sold[ii] * cur.lamlast + acc[ii];
            Sreg[mt] = sold;
            bf16x4 sb4 = { (bf16)sold[0], (bf16)sold[1], (bf16)sold[2], (bf16)sold[3] };
            *(bf16x4*)(&Swr[ln * 136 + kt * 16 + qd * 4]) = sb4;
        }
        __syncthreads();  // B3
    };

    Pref pA, pB;
    load_pref(pA, bh * NC_, 0, (size_t)bh * T_ * 128, tid, wave, ln, qd, bh, vbase,
              qb, kb, vb, kTb, Tg, Mg, lamg, ratiog, bbuf);
    __syncthreads();

#pragma unroll 1
    for (int nc2 = 0; nc2 < NC_; nc2 += 2) {
        chunk_body(pA, pB, nc2,     &Sbf[0][0], &Sbf[1][0]);
        chunk_body(pB, pA, nc2 + 1, &Sbf[1][0], &Sbf[0][0]);
    }
}

// ---------------- o = o*silu(z); RMSNorm over DV; -> bf16 ----------------
// 4 heads per 256-thread block (head = one 64-lane wave).
__global__ __launch_bounds__(256) void gated_norm_kernel(
    const float* __restrict__ ob, const bf16* __restrict__ z,
    const float* __restrict__ nw, bf16* __restrict__ onorm) {
    const int idx = blockIdx.x * 4 + (threadIdx.x >> 6);  // B*T*H
    const int h = idx & (H_ - 1);
    const int bt = idx >> 4;
    const int t = bt & (T_ - 1);
    const int b = bt >> 11;
    const int tid = threadIdx.x & 63;
    const size_t obase = (((size_t)(b * H_ + h)) * T_ + t) * 128;
    const size_t zbase = (size_t)bt * 2048 + (h << 7);
    float o1 = ob[obase + tid], o2 = ob[obase + tid + 64];
    const float z1 = (float)z[zbase + tid], z2 = (float)z[zbase + tid + 64];
    o1 *= z1 / (1.f + __expf(-z1));
    o2 *= z2 / (1.f + __expf(-z2));
    float ss = o1 * o1 + o2 * o2;
#pragma unroll
    for (int o = 1; o < 64; o <<= 1) ss += __shfl_xor(ss, o);
    const float scale = rsqrtf(ss * (1.f / 128.f) + 1e-6f);
    onorm[zbase + tid]      = (bf16)(o1 * scale * nw[tid]);
    onorm[zbase + tid + 64] = (bf16)(o2 * scale * nw[tid + 64]);
}

extern "C" void kernel_launch(void* const* d_in, const int* in_sizes, int n_in,
                              void* d_out, int out_size, void* d_ws, size_t ws_size,
                              hipStream_t stream) {
    const float* X    = (const float*)d_in[0];
    const float* Wqkv = (const float*)d_in[1];
    const float* cw   = (const float*)d_in[2];
    const float* Wz   = (const float*)d_in[3];
    const float* Wb   = (const float*)d_in[4];
    const float* Wa   = (const float*)d_in[5];
    const float* dtb  = (const float*)d_in[6];
    const float* Alog = (const float*)d_in[7];
    const float* nw   = (const float*)d_in[8];
    const float* Wout = (const float*)d_in[9];
    float* out = (float*)d_out;

    char* ws = (char*)d_ws;
    size_t off = 0;
    auto alloc = [&](size_t bytes) -> char* {
        char* p = ws + off;
        off += (bytes + 255) & ~(size_t)255;
        return p;
    };
    bf16*  Xb      = (bf16*)alloc((size_t)B_ * T_ * D_ * 2);
    // Wcat = [Wqkv^T (6144 rows) ; Wz^T (2048 rows)] -> 8192 x 2048 bf16
    char*  wcat_p  = alloc((size_t)8192 * 2048 * 2);
    bf16*  Wcat    = (bf16*)wcat_p;
    bf16*  Woutt   = (bf16*)alloc((size_t)D_ * D_ * 2);
    bf16*  Wba     = (bf16*)alloc((size_t)32 * 2048 * 2);
    char*  mixed_p = alloc((size_t)B_ * T_ * CONV_DIM_ * 2);
    bf16*  mixedb  = (bf16*)mixed_p;
    bf16*  zb      = (bf16*)alloc((size_t)B_ * T_ * D_ * 2);
    bf16*  kbuf    = (bf16*)alloc((size_t)B_ * T_ * D_ * 2);
    bf16*  vbuf    = (bf16*)alloc((size_t)B_ * T_ * D_ * 2);
    bf16*  kTb     = (bf16*)alloc((size_t)B_ * H_ * 128 * T_ * 2);
    float* gbuf    = (float*)alloc((size_t)B_ * T_ * H_ * 4);
    float* bbuf    = (float*)alloc((size_t)B_ * T_ * H_ * 4);
    bf16*  Tg      = (bf16*)alloc((size_t)1024 * 4096 * 2);
    bf16*  Mg      = (bf16*)alloc((size_t)1024 * 4096 * 2);
    float* lamg    = (float*)alloc((size_t)1024 * 64 * 4);
    float* ratiog  = (float*)alloc((size_t)1024 * 64 * 4);
    // aliases (stream-order safe):
    bf16*  qbuf    = (bf16*)wcat_p;
    float* obuf    = (float*)mixed_p;
    bf16*  onorm   = (bf16*)Xb;

    cvt_wba_kernel<<<dim3(8192 + 128), dim3(256), 0, stream>>>(
        X, Xb, B_ * T_ * D_ / 4, Wb, Wa, Wba);
    transpose3_kernel<<<dim3(20480), dim3(256), 0, stream>>>(Wqkv, Wz, Wout, Wcat, Woutt);

    // fused QKV+Z projection: [4096 x 2048] @ [2048 x 8192]; cols<6144 -> mixed, else -> z
    gemm256_kernel<<<dim3(8192 / 256, B_ * T_ / 256), dim3(512), 0, stream>>>(
        Xb, Wcat, mixedb, zb, B_ * T_, 8192, D_, CONV_DIM_, CONV_DIM_, D_);

    conv_gbeta_kernel<<<dim3(12288 + 64), dim3(256), 0, stream>>>(
        mixedb, cw, qbuf, kbuf, vbuf, Xb, Wba, dtb, Alog, gbuf, bbuf);

    qkkt_prep_kernel<<<dim3(1024), dim3(256), 0, stream>>>(
        qbuf, kbuf, gbuf, bbuf, lamg, ratiog, Tg, Mg, kTb);
    seq_kernel<<<dim3(256), dim3(256), 0, stream>>>(qbuf, kbuf, vbuf, kTb, Tg, Mg, lamg, ratiog, bbuf, obuf);

    gated_norm_kernel<<<dim3(B_ * T_ * H_ / 4), dim3(256), 0, stream>>>(obuf, zb, nw, onorm);

    gemm_kernel<float><<<dim3(D_ / 128, B_ * T_ / 128), dim3(256), 0, stream>>>(
        onorm, Woutt, out, B_ * T_, D_, D_);
}